// Round 5
// baseline (2718.908 us; speedup 1.0000x reference)
//
#include <hip/hip_runtime.h>
#include <stdint.h>

#define TT 256
#define NS 4
#define CH 16

typedef __attribute__((ext_vector_type(4))) float f32x4;
typedef __attribute__((ext_vector_type(8))) short s16x8;

#define DEV static __device__ __forceinline__

DEV short f2bf(float f){
  union{float f; uint32_t u;} v; v.f = f;
  uint32_t r = v.u + 0x7fffu + ((v.u>>16)&1u);
  return (short)(r>>16);
}
DEV float bf2f(uint32_t u16){
  union{uint32_t u; float f;} v; v.u = u16<<16; return v.f;
}
DEV uint32_t pk2(float a, float b){
  return (uint32_t)(uint16_t)f2bf(a) | ((uint32_t)(uint16_t)f2bf(b)<<16);
}
DEV float sigm(float x){ return 1.f/(1.f + __expf(-x)); }
DEV float tanh_f(float x){ float e = __expf(2.f*x); return 1.f - 2.f/(e+1.f); }
DEV f32x4 MFMA(s16x8 a, s16x8 b, f32x4 c){
  return __builtin_amdgcn_mfma_f32_16x16x32_bf16(a, b, c, 0, 0, 0);
}
DEV s16x8 cvt8(const float* p){
  f32x4 a = *(const f32x4*)p;
  f32x4 b = *(const f32x4*)(p+4);
  s16x8 o;
  o[0]=f2bf(a[0]); o[1]=f2bf(a[1]); o[2]=f2bf(a[2]); o[3]=f2bf(a[3]);
  o[4]=f2bf(b[0]); o[5]=f2bf(b[1]); o[6]=f2bf(b[2]); o[7]=f2bf(b[3]);
  return o;
}
// barrier that drains LDS only (global stores/loads stay in flight)
DEV void bar_lds(){
  asm volatile("s_waitcnt lgkmcnt(0)" ::: "memory");
  __builtin_amdgcn_s_barrier();
}

// flush 8 steps x NS rows x 128 cols of bf16 h from LDS to global, coalesced.
// src points at the 8KB region; all 512 threads participate.
DEV void flush_rows(const char* src, uint16_t* __restrict__ hdst, int t0,
                    int dir, int BR, int bg, int tid){
  int row = tid >> 4, part = tid & 15;       // 32 rows x 16 parts
  int tp = t0 + (row >> 2), b = row & 3;
  int tg = dir ? (TT-1-tp) : tp;
  s16x8 v = *(const s16x8*)(src + row*256 + part*16);
  *(s16x8*)(hdst + ((size_t)tg*BR + bg*NS + b)*256 + dir*128 + part*8) = v;
}

// ================= BiLSTM layer 0 (LN fused; 6 -> 128/dir), NS=4 =================
__global__ __launch_bounds__(512,4) void lstm0_kernel(
    const float* __restrict__ x, const float* __restrict__ lng,
    const float* __restrict__ lnb,
    const float* __restrict__ Wih0, const float* __restrict__ Whh0,
    const float* __restrict__ bih0, const float* __restrict__ bhh0,
    uint16_t* __restrict__ h0, int nb, int BR, int b_off)
{
  const int dir = blockIdx.x / nb, bg = blockIdx.x % nb;
  const int tid = threadIdx.x, w = tid>>6, l = tid&63;
  const int lm = l&15, lk = l>>4;
  const int gb = b_off + bg*NS;

  __shared__ short hbuf[2][2048];     // 8 KB, XOR(row<<4) swizzle
  __shared__ short xnbf[TT*NS*8];     // 16 KB: [t][r][8] bf16 (K=6 padded)
  __shared__ short houts[2][4096];    // 16 KB: 2 regions x 8 steps x 4 rows x 128

  for (int i=tid; i<4096; i+=512) ((short*)hbuf)[i] = 0;

  // LN fused staging
  for (int pr=tid; pr<TT*NS; pr+=512){
    int r = pr >> 8, t = pr & 255;
    const float* px = x + ((size_t)(gb+r)*TT + t)*6;
    float v[6]; float mu=0.f, var=0.f;
    #pragma unroll
    for (int d=0; d<6; ++d){ v[d]=px[d]; mu+=v[d]; }
    mu *= (1.f/6.f);
    #pragma unroll
    for (int d=0; d<6; ++d){ float dd=v[d]-mu; var+=dd*dd; }
    float rs = rsqrtf(var*(1.f/6.f) + 1e-5f);
    s16x8 vv;
    #pragma unroll
    for (int d=0; d<6; ++d) vv[d] = f2bf((v[d]-mu)*rs*lng[d] + lnb[d]);
    vv[6]=0; vv[7]=0;
    *(s16x8*)&xnbf[(t*NS + r)*8] = vv;
  }

  const int c = w*16 + lm;
  s16x8 bw[4][4], bx[4];
  float biasc[4];
  #pragma unroll
  for (int G=0; G<4; ++G){
    const int n = G*128 + c;
    biasc[G] = bih0[dir*512+n] + bhh0[dir*512+n];
    #pragma unroll
    for (int kt=0; kt<4; ++kt)
      bw[G][kt] = cvt8(Whh0 + ((size_t)(dir*512+n))*128 + kt*32 + lk*8);
    s16x8 tx;
    #pragma unroll
    for (int j=0; j<8; ++j){
      int k = lk*8 + j;
      tx[j] = (k<6) ? f2bf(Wih0[(size_t)(dir*512+n)*6 + k]) : (short)0;
    }
    bx[G] = tx;
  }

  const int r0 = ((l>>4)&1)*4 + ((l<32)?0:2);
  float cst[2] = {0.f, 0.f};
  __syncthreads();

  for (int t=0; t<TT; ++t){
    const int tt = dir ? (TT-1-t) : t;
    const int rd = t & 1;
    s16x8 ah[4];
    #pragma unroll
    for (int kt=0; kt<4; ++kt){
      int off = rd*4096 + lm*256 + ((kt*64 + lk*16) ^ (lm<<4));
      ah[kt] = *(const s16x8*)((const char*)hbuf + off);
    }
    s16x8 ax = {0,0,0,0,0,0,0,0};
    if (l < NS) ax = *(const s16x8*)&xnbf[(tt*NS + l)*8];

    f32x4 acc[4];
    #pragma unroll
    for (int G=0; G<4; ++G){
      f32x4 a = {0.f,0.f,0.f,0.f};
      #pragma unroll
      for (int kt=0; kt<4; ++kt) a = MFMA(ah[kt], bw[G][kt], a);
      a = MFMA(ax, bx[G], a);
      acc[G] = a;
    }

    float g0[4], g1[4];
    #pragma unroll
    for (int G=0; G<4; ++G){
      float o2 = __shfl(acc[G][2], l & 31);
      float o3 = __shfl(acc[G][3], l & 31);
      g0[G] = ((l<32) ? acc[G][0] : o2) + biasc[G];
      g1[G] = ((l<32) ? acc[G][1] : o3) + biasc[G];
    }
    float hv[2];
    {
      float cc = sigm(g0[1])*cst[0] + sigm(g0[0])*tanh_f(g0[2]);
      cst[0] = cc; hv[0] = sigm(g0[3])*tanh_f(cc);
      cc = sigm(g1[1])*cst[1] + sigm(g1[0])*tanh_f(g1[2]);
      cst[1] = cc; hv[1] = sigm(g1[3])*tanh_f(cc);
    }

    if (r0 < NS){
      #pragma unroll
      for (int q=0; q<2; ++q){
        int r = r0 + q;
        short hb = f2bf(hv[q]);
        *(short*)((char*)hbuf + (rd^1)*4096 + r*256 + ((c*2) ^ (r<<4))) = hb;
        *(short*)((char*)houts + ((t>>3)&1)*8192 + ((t&7)*4 + r)*256 + c*2) = hb;
      }
    }
    bar_lds();
    if ((t&7) == 7)
      flush_rows((const char*)houts + ((t>>3)&1)*8192, h0, t-7, dir, BR, bg, tid);
  }
}

// ============ BiLSTM layer 1 (256 -> 128/dir), fused xp, NS=4, CH=16 ============
__global__ __launch_bounds__(512,4) void lstm1_kernel(
    const uint16_t* __restrict__ h0, const float* __restrict__ Wih1,
    const float* __restrict__ Whh1, const float* __restrict__ bih1,
    const float* __restrict__ bhh1, uint16_t* __restrict__ h1,
    int nb, int BR)
{
  const int dir = blockIdx.x / nb, bg = blockIdx.x % nb;
  const int tid = threadIdx.x, w = tid>>6, l = tid&63;
  const int lm = l&15, lk = l>>4;

  __shared__ short hbuf[2][2048];     // 8 KB
  __shared__ short abuf[2][16384];    // 64 KB: CH*NS=64 rows x 256 cols, dbuf

  for (int i=tid; i<4096; i+=512) ((short*)hbuf)[i] = 0;

  const int c = w*16 + lm;
  s16x8 bw[4][4];
  float biasv[4];
  #pragma unroll
  for (int G=0; G<4; ++G){
    const int n = G*128 + c;
    biasv[G] = bih1[dir*512+n] + bhh1[dir*512+n];
    #pragma unroll
    for (int kt=0; kt<4; ++kt)
      bw[G][kt] = cvt8(Whh1 + ((size_t)(dir*512+n))*128 + kt*32 + lk*8);
  }

  const int r0 = ((l>>4)&1)*4 + ((l<32)?0:2);
  float cst[2] = {0.f,0.f};
  uint32_t xpk[4][4][2];
  s16x8 vst[4];

  // prologue: stage chunk 0
  #pragma unroll
  for (int it=0; it<4; ++it){
    int sid = it*512 + tid, row = sid>>5, sl = sid&31, s = row>>2, b = row&3;
    int tg = dir ? (TT-1-s) : s;
    vst[it] = *(const s16x8*)(h0 + ((size_t)tg*BR + bg*NS + b)*256 + sl*8);
  }
  #pragma unroll
  for (int it=0; it<4; ++it){
    int sid = it*512 + tid, row = sid>>5, sl = sid&31;
    *(s16x8*)((char*)abuf + row*512 + ((sl ^ (row&15))<<4)) = vst[it];
  }
  __syncthreads();

  for (int ch=0; ch<TT/CH; ++ch){
    const int cur = ch & 1;
    const char* ab = (const char*)abuf + cur*32768;

    // issue next chunk's loads early (land during phase A)
    if (ch < TT/CH-1){
      #pragma unroll
      for (int it=0; it<4; ++it){
        int sid = it*512 + tid, row = sid>>5, sl = sid&31, s = row>>2, b = row&3;
        int ts = (ch+1)*CH + s;
        int tg = dir ? (TT-1-ts) : ts;
        vst[it] = *(const s16x8*)(h0 + ((size_t)tg*BR + bg*NS + b)*256 + sl*8);
      }
    }

    // ---- phase A: xp for CH steps (G-outer, bfr reused over 4 m-tiles) ----
    #pragma unroll
    for (int G=0; G<4; ++G){
      f32x4 acc[4];
      #pragma unroll
      for (int mt=0; mt<4; ++mt) acc[mt] = (f32x4){biasv[G],biasv[G],biasv[G],biasv[G]};
      #pragma unroll
      for (int kt=0; kt<8; ++kt){
        s16x8 bfr = cvt8(Wih1 + ((size_t)(dir*512 + G*128 + c))*256 + kt*32 + lk*8);
        #pragma unroll
        for (int mt=0; mt<4; ++mt){
          int row = mt*16 + lm;
          s16x8 afr = *(const s16x8*)(ab + row*512 + (((kt*4+lk) ^ (row&15))<<4));
          acc[mt] = MFMA(afr, bfr, acc[mt]);
        }
      }
      #pragma unroll
      for (int mt=0; mt<4; ++mt){
        xpk[G][mt][0] = pk2(acc[mt][0], acc[mt][1]);
        xpk[G][mt][1] = pk2(acc[mt][2], acc[mt][3]);
      }
    }

    // write staged regs -> other abuf (free since its flush finished last chunk)
    if (ch < TT/CH-1){
      char* ab2 = (char*)abuf + (cur^1)*32768;
      #pragma unroll
      for (int it=0; it<4; ++it){
        int sid = it*512 + tid, row = sid>>5, sl = sid&31;
        *(s16x8*)(ab2 + row*512 + ((sl ^ (row&15))<<4)) = vst[it];
      }
    }

    // ---- phase B: CH recurrent steps; houts reuses abuf[cur][0:16KB] ----
    #pragma unroll
    for (int s=0; s<CH; ++s){
      const int gs = ch*CH + s;
      const int rd = gs & 1;
      const int src = (s&3)*16 + lm;

      f32x4 acc4[4];
      #pragma unroll
      for (int G=0; G<4; ++G){
        uint32_t p0 = (uint32_t)__shfl((int)xpk[G][s>>2][0], src);
        uint32_t p1 = (uint32_t)__shfl((int)xpk[G][s>>2][1], src);
        acc4[G] = (f32x4){bf2f(p0&0xffffu), bf2f(p0>>16), bf2f(p1&0xffffu), bf2f(p1>>16)};
      }

      s16x8 ah[4];
      #pragma unroll
      for (int kt=0; kt<4; ++kt){
        int off = rd*4096 + lm*256 + ((kt*64 + lk*16) ^ (lm<<4));
        ah[kt] = *(const s16x8*)((const char*)hbuf + off);
      }
      #pragma unroll
      for (int G=0; G<4; ++G){
        #pragma unroll
        for (int kt=0; kt<4; ++kt)
          acc4[G] = MFMA(ah[kt], bw[G][kt], acc4[G]);
      }

      float g0[4], g1[4];
      #pragma unroll
      for (int G=0; G<4; ++G){
        float o2 = __shfl(acc4[G][2], l & 31);
        float o3 = __shfl(acc4[G][3], l & 31);
        g0[G] = (l<32) ? acc4[G][0] : o2;
        g1[G] = (l<32) ? acc4[G][1] : o3;
      }
      float hv[2];
      float cc = sigm(g0[1])*cst[0] + sigm(g0[0])*tanh_f(g0[2]);
      cst[0] = cc; hv[0] = sigm(g0[3])*tanh_f(cc);
      cc = sigm(g1[1])*cst[1] + sigm(g1[0])*tanh_f(g1[2]);
      cst[1] = cc; hv[1] = sigm(g1[3])*tanh_f(cc);

      if (r0 < NS){
        #pragma unroll
        for (int q=0; q<2; ++q){
          int r = r0 + q;
          short hb = f2bf(hv[q]);
          *(short*)((char*)hbuf + (rd^1)*4096 + r*256 + ((c*2) ^ (r<<4))) = hb;
          *(short*)((char*)ab + (s>>3)*8192 + ((s&7)*4 + r)*256 + c*2) = hb;
        }
      }
      bar_lds();
      if (s == 7 || s == CH-1)
        flush_rows(ab + (s>>3)*8192, h1, ch*CH + (s>>3)*8, dir, BR, bg, tid);
    }
    bar_lds();   // protect last flush reads from next chunk's staging writes
  }
}

// ================= attention scores =================
__global__ __launch_bounds__(256,2) void scores_kernel(
    const uint16_t* __restrict__ h1, const float* __restrict__ Wa1,
    const float* __restrict__ ba1, const float* __restrict__ Wa2,
    const float* __restrict__ ba2, float* __restrict__ scores,
    int nbb, int BR)
{
  const int bx = blockIdx.x;
  const int t = bx / nbb, bb = (bx - t*nbb) * 64;
  const int tid = threadIdx.x, w = tid>>6, l = tid&63;
  const int lm = l&15, lk = l>>4;
  __shared__ short abuf[64*256];
  __shared__ float scred[4][64];

  #pragma unroll
  for (int it=0; it<8; ++it){
    int sid = it*256 + tid, row = sid>>5, sl = sid&31;
    s16x8 v = *(const s16x8*)(h1 + ((size_t)t*BR + bb + row)*256 + sl*8);
    *(s16x8*)((char*)abuf + row*512 + ((sl ^ (row&15))<<4)) = v;
  }

  s16x8 bwa[2][8]; float b1v[2], wa2v[2];
  #pragma unroll
  for (int nt=0; nt<2; ++nt){
    int n = w*32 + nt*16 + lm;
    b1v[nt] = ba1[n]; wa2v[nt] = Wa2[n];
    #pragma unroll
    for (int kt=0; kt<8; ++kt)
      bwa[nt][kt] = cvt8(Wa1 + (size_t)n*256 + kt*32 + lk*8);
  }
  __syncthreads();

  #pragma unroll
  for (int mt=0; mt<4; ++mt){
    f32x4 a0 = {b1v[0],b1v[0],b1v[0],b1v[0]};
    f32x4 a1 = {b1v[1],b1v[1],b1v[1],b1v[1]};
    #pragma unroll
    for (int kt=0; kt<8; ++kt){
      int row = mt*16 + lm;
      s16x8 af = *(const s16x8*)((const char*)abuf + row*512 + (((kt*4+lk) ^ (row&15))<<4));
      a0 = MFMA(af, bwa[0][kt], a0);
      a1 = MFMA(af, bwa[1][kt], a1);
    }
    #pragma unroll
    for (int j=0; j<4; ++j){
      float pj = tanh_f(a0[j])*wa2v[0] + tanh_f(a1[j])*wa2v[1];
      #pragma unroll
      for (int m=1; m<16; m<<=1) pj += __shfl_xor(pj, m);
      if (lm == 0) scred[w][mt*16 + lk*4 + j] = pj;
    }
  }
  __syncthreads();
  if (tid < 64){
    float s = scred[0][tid]+scred[1][tid]+scred[2][tid]+scred[3][tid] + ba2[0];
    scores[(size_t)(bb+tid)*TT + t] = s;
  }
}

// ================= softmax over T + context =================
__global__ __launch_bounds__(256,2) void ctx_kernel(
    const uint16_t* __restrict__ h1, const float* __restrict__ scores,
    float* __restrict__ context, int BR)
{
  const int b = blockIdx.x, tid = threadIdx.x;
  __shared__ float at[TT];
  __shared__ float red[8];
  float sc = scores[(size_t)b*TT + tid];
  float m = sc;
  #pragma unroll
  for (int d=1; d<64; d<<=1) m = fmaxf(m, __shfl_xor(m, d));
  if ((tid&63)==0) red[tid>>6] = m;
  __syncthreads();
  m = fmaxf(fmaxf(red[0],red[1]), fmaxf(red[2],red[3]));
  float e = __expf(sc - m);
  float s = e;
  #pragma unroll
  for (int d=1; d<64; d<<=1) s += __shfl_xor(s, d);
  if ((tid&63)==0) red[4+(tid>>6)] = s;
  __syncthreads();
  s = red[4]+red[5]+red[6]+red[7];
  at[tid] = e / s;
  __syncthreads();

  float acc = 0.f;
  const uint16_t* hp = h1 + (size_t)b*256 + tid;
  #pragma unroll 4
  for (int t2=0; t2<TT; ++t2) acc += at[t2] * bf2f(hp[(size_t)t2*BR*256]);
  context[(size_t)b*256 + tid] = acc;
}

// ================= head =================
__global__ __launch_bounds__(128,2) void head_kernel(
    const float* __restrict__ ctx, const float* __restrict__ Wf1,
    const float* __restrict__ bf1, const float* __restrict__ g2,
    const float* __restrict__ b2, const float* __restrict__ Wf2,
    const float* __restrict__ bf2v, float* __restrict__ out, int b_off)
{
  const int b = blockIdx.x, tid = threadIdx.x;
  __shared__ float cx[256];
  __shared__ float zb[128];
  __shared__ float red[4];
  cx[tid]       = ctx[(size_t)b*256 + tid];
  cx[128+tid]   = ctx[(size_t)b*256 + 128 + tid];
  __syncthreads();
  float y = bf1[tid];
  const float* wr = Wf1 + (size_t)tid*256;
  #pragma unroll 8
  for (int k=0; k<256; ++k) y += cx[k]*wr[k];
  float s = y;
  #pragma unroll
  for (int d=1; d<64; d<<=1) s += __shfl_xor(s, d);
  if ((tid&63)==0) red[tid>>6] = s;
  __syncthreads();
  float mu = (red[0]+red[1])*(1.f/128.f);
  float dv = y - mu;
  float q = dv*dv;
  #pragma unroll
  for (int d=1; d<64; d<<=1) q += __shfl_xor(q, d);
  if ((tid&63)==0) red[2+(tid>>6)] = q;
  __syncthreads();
  float var = (red[2]+red[3])*(1.f/128.f);
  float z = dv*rsqrtf(var + 1e-5f)*g2[tid] + b2[tid];
  z = fmaxf(z, 0.f);
  zb[tid] = z;
  __syncthreads();
  if (tid < 5){
    float o = bf2v[tid];
    const float* wp = Wf2 + (size_t)tid*128;
    for (int k=0; k<128; ++k) o += zb[k]*wp[k];
    out[(size_t)(b_off + b)*5 + tid] = o;
  }
}

extern "C" void kernel_launch(void* const* d_in, const int* in_sizes, int n_in,
                              void* d_out, int out_size, void* d_ws, size_t ws_size,
                              hipStream_t stream)
{
  const float* x    = (const float*)d_in[0];
  const float* ln_g = (const float*)d_in[1];
  const float* ln_b = (const float*)d_in[2];
  const float* Wih0 = (const float*)d_in[3];
  const float* Whh0 = (const float*)d_in[4];
  const float* bih0 = (const float*)d_in[5];
  const float* bhh0 = (const float*)d_in[6];
  const float* Wih1 = (const float*)d_in[7];
  const float* Whh1 = (const float*)d_in[8];
  const float* bih1 = (const float*)d_in[9];
  const float* bhh1 = (const float*)d_in[10];
  const float* Wa1  = (const float*)d_in[11];
  const float* ba1  = (const float*)d_in[12];
  const float* Wa2  = (const float*)d_in[13];
  const float* ba2  = (const float*)d_in[14];
  const float* Wf1  = (const float*)d_in[15];
  const float* bf1  = (const float*)d_in[16];
  const float* ln2g = (const float*)d_in[17];
  const float* ln2b = (const float*)d_in[18];
  const float* Wf2  = (const float*)d_in[19];
  const float* bf2  = (const float*)d_in[20];
  float* out = (float*)d_out;

  char* wsb = (char*)d_ws;
  const size_t HBf = (size_t)TT*1024*256*2;   // 134,217,728

  if (ws_size >= 2*HBf){
    // ---------- FULL: whole batch in one pass; scores/ctx alias dead h0 ----------
    uint16_t* h0 = (uint16_t*)wsb;
    uint16_t* h1 = (uint16_t*)(wsb + HBf);
    float* scoresP = (float*)wsb;
    float* ctxP    = (float*)(wsb + (size_t)1024*TT*4);

    lstm0_kernel<<<512, 512, 0, stream>>>(x, ln_g, ln_b, Wih0, Whh0, bih0, bhh0,
                                          h0, 256, 1024, 0);
    lstm1_kernel<<<512, 512, 0, stream>>>(h0, Wih1, Whh1, bih1, bhh1, h1, 256, 1024);
    scores_kernel<<<TT*16, 256, 0, stream>>>(h1, Wa1, ba1, Wa2, ba2, scoresP, 16, 1024);
    ctx_kernel   <<<1024, 256, 0, stream>>>(h1, scoresP, ctxP, 1024);
    head_kernel  <<<1024, 128, 0, stream>>>(ctxP, Wf1, bf1, ln2g, ln2b, Wf2, bf2, out, 0);
  } else {
    // ---------- fallback: rounds of BR samples ----------
    int BR = 512;
    while (BR > 64){
      size_t HB = (size_t)TT*BR*256*2;
      if (2*HB + 2*((size_t)BR*256*4) <= ws_size) break;
      BR >>= 1;
    }
    const size_t HB = (size_t)TT*BR*256*2;
    uint16_t* h0 = (uint16_t*)wsb;
    uint16_t* h1 = (uint16_t*)(wsb + HB);
    float* scoresP = (float*)(wsb + 2*HB);
    float* ctxP    = (float*)(wsb + 2*HB + (size_t)BR*256*4);
    const int nb = BR/NS;

    for (int b_off = 0; b_off < 1024; b_off += BR){
      lstm0_kernel<<<2*nb, 512, 0, stream>>>(x, ln_g, ln_b, Wih0, Whh0, bih0, bhh0,
                                             h0, nb, BR, b_off);
      lstm1_kernel<<<2*nb, 512, 0, stream>>>(h0, Wih1, Whh1, bih1, bhh1, h1, nb, BR);
      scores_kernel<<<TT*(BR/64), 256, 0, stream>>>(h1, Wa1, ba1, Wa2, ba2, scoresP,
                                                    BR/64, BR);
      ctx_kernel   <<<BR, 256, 0, stream>>>(h1, scoresP, ctxP, BR);
      head_kernel  <<<BR, 128, 0, stream>>>(ctxP, Wf1, bf1, ln2g, ln2b, Wf2, bf2,
                                            out, b_off);
    }
  }
}

// Round 6
// 1952.583 us; speedup vs baseline: 1.3925x; 1.3925x over previous
//
#include <hip/hip_runtime.h>
#include <stdint.h>

#define TT 256
#define NS 4
#define CH 16

typedef __attribute__((ext_vector_type(4))) float f32x4;
typedef __attribute__((ext_vector_type(8))) short s16x8;

#define DEV static __device__ __forceinline__

// prepped bf16 Wih1 fragments: [dir][ntg(32)][kt(8)][lane(64)][8]
__device__ uint16_t g_W1f[2*32*8*64*8];

DEV short f2bf(float f){
  union{float f; uint32_t u;} v; v.f = f;
  uint32_t r = v.u + 0x7fffu + ((v.u>>16)&1u);
  return (short)(r>>16);
}
DEV float bf2f(uint32_t u16){
  union{uint32_t u; float f;} v; v.u = u16<<16; return v.f;
}
DEV uint32_t pk2(float a, float b){
  return (uint32_t)(uint16_t)f2bf(a) | ((uint32_t)(uint16_t)f2bf(b)<<16);
}
DEV float sigm(float x){ return 1.f/(1.f + __expf(-x)); }
DEV float tanh_f(float x){ float e = __expf(2.f*x); return 1.f - 2.f/(e+1.f); }
DEV f32x4 MFMA(s16x8 a, s16x8 b, f32x4 c){
  return __builtin_amdgcn_mfma_f32_16x16x32_bf16(a, b, c, 0, 0, 0);
}
DEV s16x8 cvt8(const float* p){
  f32x4 a = *(const f32x4*)p;
  f32x4 b = *(const f32x4*)(p+4);
  s16x8 o;
  o[0]=f2bf(a[0]); o[1]=f2bf(a[1]); o[2]=f2bf(a[2]); o[3]=f2bf(a[3]);
  o[4]=f2bf(b[0]); o[5]=f2bf(b[1]); o[6]=f2bf(b[2]); o[7]=f2bf(b[3]);
  return o;
}
// barrier that drains LDS only (global stores/loads stay in flight)
DEV void bar_lds(){
  asm volatile("s_waitcnt lgkmcnt(0)" ::: "memory");
  __builtin_amdgcn_s_barrier();
}

// flush 8 steps x NS rows x 128 cols of bf16 h from LDS to global, coalesced.
DEV void flush_rows(const char* src, uint16_t* __restrict__ hdst, int t0,
                    int dir, int BR, int bg, int tid){
  int row = tid >> 4, part = tid & 15;       // 32 rows x 16 parts
  int tp = t0 + (row >> 2), b = row & 3;
  int tg = dir ? (TT-1-tp) : tp;
  s16x8 v = *(const s16x8*)(src + row*256 + part*16);
  *(s16x8*)(hdst + ((size_t)tg*BR + bg*NS + b)*256 + dir*128 + part*8) = v;
}

// ---------------- Wih1 -> bf16 B-fragment layout ----------------
__global__ __launch_bounds__(256) void prep_wih1(const float* __restrict__ Wih1)
{
  int tid = blockIdx.x*256 + threadIdx.x;   // 32768 total
  int l = tid & 63, kt = (tid>>6)&7, ntg = (tid>>9)&31, dir = (tid>>14)&1;
  int lm = l&15, lk = l>>4;
  int n = ntg*16 + lm;
  s16x8 o = cvt8(Wih1 + ((size_t)(dir*512 + n))*256 + kt*32 + lk*8);
  *(s16x8*)(&g_W1f[(size_t)tid*8]) = o;
}

// ================= BiLSTM layer 0 (LN fused; 6 -> 128/dir), NS=4 =================
__global__ __launch_bounds__(512,2) void lstm0_kernel(
    const float* __restrict__ x, const float* __restrict__ lng,
    const float* __restrict__ lnb,
    const float* __restrict__ Wih0, const float* __restrict__ Whh0,
    const float* __restrict__ bih0, const float* __restrict__ bhh0,
    uint16_t* __restrict__ h0, int nb, int BR, int b_off)
{
  const int dir = blockIdx.x / nb, bg = blockIdx.x % nb;
  const int tid = threadIdx.x, w = tid>>6, l = tid&63;
  const int lm = l&15, lk = l>>4;
  const int gb = b_off + bg*NS;

  __shared__ short hbuf[2][2048];     // 8 KB, XOR(row<<4) swizzle
  __shared__ short xnbf[TT*NS*8];     // 16 KB
  __shared__ short houts[2][4096];    // 16 KB

  for (int i=tid; i<4096; i+=512) ((short*)hbuf)[i] = 0;

  for (int pr=tid; pr<TT*NS; pr+=512){
    int r = pr >> 8, t = pr & 255;
    const float* px = x + ((size_t)(gb+r)*TT + t)*6;
    float v[6]; float mu=0.f, var=0.f;
    #pragma unroll
    for (int d=0; d<6; ++d){ v[d]=px[d]; mu+=v[d]; }
    mu *= (1.f/6.f);
    #pragma unroll
    for (int d=0; d<6; ++d){ float dd=v[d]-mu; var+=dd*dd; }
    float rs = rsqrtf(var*(1.f/6.f) + 1e-5f);
    s16x8 vv;
    #pragma unroll
    for (int d=0; d<6; ++d) vv[d] = f2bf((v[d]-mu)*rs*lng[d] + lnb[d]);
    vv[6]=0; vv[7]=0;
    *(s16x8*)&xnbf[(t*NS + r)*8] = vv;
  }

  const int c = w*16 + lm;
  s16x8 bw[4][4], bx[4];
  float biasc[4];
  #pragma unroll
  for (int G=0; G<4; ++G){
    const int n = G*128 + c;
    biasc[G] = bih0[dir*512+n] + bhh0[dir*512+n];
    #pragma unroll
    for (int kt=0; kt<4; ++kt)
      bw[G][kt] = cvt8(Whh0 + ((size_t)(dir*512+n))*128 + kt*32 + lk*8);
    s16x8 tx;
    #pragma unroll
    for (int j=0; j<8; ++j){
      int k = lk*8 + j;
      tx[j] = (k<6) ? f2bf(Wih0[(size_t)(dir*512+n)*6 + k]) : (short)0;
    }
    bx[G] = tx;
  }

  const int r0 = ((l>>4)&1)*4 + ((l<32)?0:2);
  float cst[2] = {0.f, 0.f};
  __syncthreads();

  for (int t=0; t<TT; ++t){
    const int tt = dir ? (TT-1-t) : t;
    const int rd = t & 1;
    s16x8 ah[4];
    #pragma unroll
    for (int kt=0; kt<4; ++kt){
      int off = rd*4096 + lm*256 + ((kt*64 + lk*16) ^ (lm<<4));
      ah[kt] = *(const s16x8*)((const char*)hbuf + off);
    }
    s16x8 ax = {0,0,0,0,0,0,0,0};
    if (l < NS) ax = *(const s16x8*)&xnbf[(tt*NS + l)*8];

    f32x4 acc[4];
    #pragma unroll
    for (int G=0; G<4; ++G){
      f32x4 a = {0.f,0.f,0.f,0.f};
      #pragma unroll
      for (int kt=0; kt<4; ++kt) a = MFMA(ah[kt], bw[G][kt], a);
      a = MFMA(ax, bx[G], a);
      acc[G] = a;
    }

    float g0[4], g1[4];
    #pragma unroll
    for (int G=0; G<4; ++G){
      float o2 = __shfl(acc[G][2], l & 31);
      float o3 = __shfl(acc[G][3], l & 31);
      g0[G] = ((l<32) ? acc[G][0] : o2) + biasc[G];
      g1[G] = ((l<32) ? acc[G][1] : o3) + biasc[G];
    }
    float hv[2];
    {
      float cc = sigm(g0[1])*cst[0] + sigm(g0[0])*tanh_f(g0[2]);
      cst[0] = cc; hv[0] = sigm(g0[3])*tanh_f(cc);
      cc = sigm(g1[1])*cst[1] + sigm(g1[0])*tanh_f(g1[2]);
      cst[1] = cc; hv[1] = sigm(g1[3])*tanh_f(cc);
    }

    if (r0 < NS){
      #pragma unroll
      for (int q=0; q<2; ++q){
        int r = r0 + q;
        short hb = f2bf(hv[q]);
        *(short*)((char*)hbuf + (rd^1)*4096 + r*256 + ((c*2) ^ (r<<4))) = hb;
        *(short*)((char*)houts + ((t>>3)&1)*8192 + ((t&7)*4 + r)*256 + c*2) = hb;
      }
    }
    bar_lds();
    if ((t&7) == 7)
      flush_rows((const char*)houts + ((t>>3)&1)*8192, h0, t-7, dir, BR, bg, tid);
  }
}

// ============ BiLSTM layer 1 (256 -> 128/dir), fused xp, NS=4, CH=16 ============
__global__ __launch_bounds__(512,2) void lstm1_kernel(
    const uint16_t* __restrict__ h0,
    const float* __restrict__ Whh1, const float* __restrict__ bih1,
    const float* __restrict__ bhh1, uint16_t* __restrict__ h1,
    int nb, int BR)
{
  const int dir = blockIdx.x / nb, bg = blockIdx.x % nb;
  const int tid = threadIdx.x, w = tid>>6, l = tid&63;
  const int lm = l&15, lk = l>>4;

  __shared__ short hbuf[2][2048];     // 8 KB
  __shared__ short abuf[2][16384];    // 64 KB: 64 rows x 256 cols, dbuf

  for (int i=tid; i<4096; i+=512) ((short*)hbuf)[i] = 0;

  const int c = w*16 + lm;
  s16x8 bw[4][4];
  float biasv[4];
  #pragma unroll
  for (int G=0; G<4; ++G){
    const int n = G*128 + c;
    biasv[G] = bih1[dir*512+n] + bhh1[dir*512+n];
    #pragma unroll
    for (int kt=0; kt<4; ++kt)
      bw[G][kt] = cvt8(Whh1 + ((size_t)(dir*512+n))*128 + kt*32 + lk*8);
  }

  const int r0 = ((l>>4)&1)*4 + ((l<32)?0:2);
  float cst[2] = {0.f,0.f};
  uint32_t xpk[4][4][2];
  s16x8 vst[4];

  // prologue: stage chunk 0
  #pragma unroll
  for (int it=0; it<4; ++it){
    int sid = it*512 + tid, row = sid>>5, sl = sid&31, s = row>>2, b = row&3;
    int tg = dir ? (TT-1-s) : s;
    vst[it] = *(const s16x8*)(h0 + ((size_t)tg*BR + bg*NS + b)*256 + sl*8);
  }
  #pragma unroll
  for (int it=0; it<4; ++it){
    int sid = it*512 + tid, row = sid>>5, sl = sid&31;
    *(s16x8*)((char*)abuf + row*512 + ((sl ^ (row&15))<<4)) = vst[it];
  }
  __syncthreads();

  for (int ch=0; ch<TT/CH; ++ch){
    const int cur = ch & 1;
    const char* ab = (const char*)abuf + cur*32768;

    // issue next chunk's loads early (land during phase A)
    if (ch < TT/CH-1){
      #pragma unroll
      for (int it=0; it<4; ++it){
        int sid = it*512 + tid, row = sid>>5, sl = sid&31, s = row>>2, b = row&3;
        int ts = (ch+1)*CH + s;
        int tg = dir ? (TT-1-ts) : ts;
        vst[it] = *(const s16x8*)(h0 + ((size_t)tg*BR + bg*NS + b)*256 + sl*8);
      }
    }

    // ---- phase A: xp for CH steps (G-outer, prepped bf16 weight fragments) ----
    #pragma unroll
    for (int G=0; G<4; ++G){
      f32x4 acc[4];
      #pragma unroll
      for (int mt=0; mt<4; ++mt) acc[mt] = (f32x4){biasv[G],biasv[G],biasv[G],biasv[G]};
      #pragma unroll
      for (int kt=0; kt<8; ++kt){
        s16x8 bfr = *(const s16x8*)(&g_W1f[(((size_t)(dir*32 + G*8 + w)*8 + kt)*64 + l)*8]);
        #pragma unroll
        for (int mt=0; mt<4; ++mt){
          int row = mt*16 + lm;
          s16x8 afr = *(const s16x8*)(ab + row*512 + (((kt*4+lk) ^ (row&15))<<4));
          acc[mt] = MFMA(afr, bfr, acc[mt]);
        }
      }
      #pragma unroll
      for (int mt=0; mt<4; ++mt){
        xpk[G][mt][0] = pk2(acc[mt][0], acc[mt][1]);
        xpk[G][mt][1] = pk2(acc[mt][2], acc[mt][3]);
      }
    }

    // write staged regs -> other abuf (its readers finished last chunk)
    if (ch < TT/CH-1){
      char* ab2 = (char*)abuf + (cur^1)*32768;
      #pragma unroll
      for (int it=0; it<4; ++it){
        int sid = it*512 + tid, row = sid>>5, sl = sid&31;
        *(s16x8*)(ab2 + row*512 + ((sl ^ (row&15))<<4)) = vst[it];
      }
    }

    // ---- phase B: CH recurrent steps; houts reuses abuf[cur] ----
    #pragma unroll
    for (int s=0; s<CH; ++s){
      const int gs = ch*CH + s;
      const int rd = gs & 1;
      const int src = (s&3)*16 + lm;

      f32x4 acc4[4];
      #pragma unroll
      for (int G=0; G<4; ++G){
        uint32_t p0 = (uint32_t)__shfl((int)xpk[G][s>>2][0], src);
        uint32_t p1 = (uint32_t)__shfl((int)xpk[G][s>>2][1], src);
        acc4[G] = (f32x4){bf2f(p0&0xffffu), bf2f(p0>>16), bf2f(p1&0xffffu), bf2f(p1>>16)};
      }

      s16x8 ah[4];
      #pragma unroll
      for (int kt=0; kt<4; ++kt){
        int off = rd*4096 + lm*256 + ((kt*64 + lk*16) ^ (lm<<4));
        ah[kt] = *(const s16x8*)((const char*)hbuf + off);
      }
      #pragma unroll
      for (int G=0; G<4; ++G){
        #pragma unroll
        for (int kt=0; kt<4; ++kt)
          acc4[G] = MFMA(ah[kt], bw[G][kt], acc4[G]);
      }

      float g0[4], g1[4];
      #pragma unroll
      for (int G=0; G<4; ++G){
        float o2 = __shfl(acc4[G][2], l & 31);
        float o3 = __shfl(acc4[G][3], l & 31);
        g0[G] = (l<32) ? acc4[G][0] : o2;
        g1[G] = (l<32) ? acc4[G][1] : o3;
      }
      float hv[2];
      float cc = sigm(g0[1])*cst[0] + sigm(g0[0])*tanh_f(g0[2]);
      cst[0] = cc; hv[0] = sigm(g0[3])*tanh_f(cc);
      cc = sigm(g1[1])*cst[1] + sigm(g1[0])*tanh_f(g1[2]);
      cst[1] = cc; hv[1] = sigm(g1[3])*tanh_f(cc);

      if (r0 < NS){
        #pragma unroll
        for (int q=0; q<2; ++q){
          int r = r0 + q;
          short hb = f2bf(hv[q]);
          *(short*)((char*)hbuf + (rd^1)*4096 + r*256 + ((c*2) ^ (r<<4))) = hb;
          *(short*)((char*)ab + (s>>3)*8192 + ((s&7)*4 + r)*256 + c*2) = hb;
        }
      }
      bar_lds();
      if (s == 7 || s == CH-1)
        flush_rows(ab + (s>>3)*8192, h1, ch*CH + (s>>3)*8, dir, BR, bg, tid);
    }
    bar_lds();   // protect last flush reads from next chunk's staging writes
  }
}

// ================= attention scores =================
__global__ __launch_bounds__(256,2) void scores_kernel(
    const uint16_t* __restrict__ h1, const float* __restrict__ Wa1,
    const float* __restrict__ ba1, const float* __restrict__ Wa2,
    const float* __restrict__ ba2, float* __restrict__ scores,
    int nbb, int BR)
{
  const int bx = blockIdx.x;
  const int t = bx / nbb, bb = (bx - t*nbb) * 64;
  const int tid = threadIdx.x, w = tid>>6, l = tid&63;
  const int lm = l&15, lk = l>>4;
  __shared__ short abuf[64*256];
  __shared__ float scred[4][64];

  #pragma unroll
  for (int it=0; it<8; ++it){
    int sid = it*256 + tid, row = sid>>5, sl = sid&31;
    s16x8 v = *(const s16x8*)(h1 + ((size_t)t*BR + bb + row)*256 + sl*8);
    *(s16x8*)((char*)abuf + row*512 + ((sl ^ (row&15))<<4)) = v;
  }

  s16x8 bwa[2][8]; float b1v[2], wa2v[2];
  #pragma unroll
  for (int nt=0; nt<2; ++nt){
    int n = w*32 + nt*16 + lm;
    b1v[nt] = ba1[n]; wa2v[nt] = Wa2[n];
    #pragma unroll
    for (int kt=0; kt<8; ++kt)
      bwa[nt][kt] = cvt8(Wa1 + (size_t)n*256 + kt*32 + lk*8);
  }
  __syncthreads();

  #pragma unroll
  for (int mt=0; mt<4; ++mt){
    f32x4 a0 = {b1v[0],b1v[0],b1v[0],b1v[0]};
    f32x4 a1 = {b1v[1],b1v[1],b1v[1],b1v[1]};
    #pragma unroll
    for (int kt=0; kt<8; ++kt){
      int row = mt*16 + lm;
      s16x8 af = *(const s16x8*)((const char*)abuf + row*512 + (((kt*4+lk) ^ (row&15))<<4));
      a0 = MFMA(af, bwa[0][kt], a0);
      a1 = MFMA(af, bwa[1][kt], a1);
    }
    #pragma unroll
    for (int j=0; j<4; ++j){
      float pj = tanh_f(a0[j])*wa2v[0] + tanh_f(a1[j])*wa2v[1];
      #pragma unroll
      for (int m=1; m<16; m<<=1) pj += __shfl_xor(pj, m);
      if (lm == 0) scred[w][mt*16 + lk*4 + j] = pj;
    }
  }
  __syncthreads();
  if (tid < 64){
    float s = scred[0][tid]+scred[1][tid]+scred[2][tid]+scred[3][tid] + ba2[0];
    scores[(size_t)(bb+tid)*TT + t] = s;
  }
}

// ================= softmax over T + context =================
__global__ __launch_bounds__(256,2) void ctx_kernel(
    const uint16_t* __restrict__ h1, const float* __restrict__ scores,
    float* __restrict__ context, int BR)
{
  const int b = blockIdx.x, tid = threadIdx.x;
  __shared__ float at[TT];
  __shared__ float red[8];
  float sc = scores[(size_t)b*TT + tid];
  float m = sc;
  #pragma unroll
  for (int d=1; d<64; d<<=1) m = fmaxf(m, __shfl_xor(m, d));
  if ((tid&63)==0) red[tid>>6] = m;
  __syncthreads();
  m = fmaxf(fmaxf(red[0],red[1]), fmaxf(red[2],red[3]));
  float e = __expf(sc - m);
  float s = e;
  #pragma unroll
  for (int d=1; d<64; d<<=1) s += __shfl_xor(s, d);
  if ((tid&63)==0) red[4+(tid>>6)] = s;
  __syncthreads();
  s = red[4]+red[5]+red[6]+red[7];
  at[tid] = e / s;
  __syncthreads();

  float acc = 0.f;
  const uint16_t* hp = h1 + (size_t)b*256 + tid;
  #pragma unroll 4
  for (int t2=0; t2<TT; ++t2) acc += at[t2] * bf2f(hp[(size_t)t2*BR*256]);
  context[(size_t)b*256 + tid] = acc;
}

// ================= head =================
__global__ __launch_bounds__(128,2) void head_kernel(
    const float* __restrict__ ctx, const float* __restrict__ Wf1,
    const float* __restrict__ bf1, const float* __restrict__ g2,
    const float* __restrict__ b2, const float* __restrict__ Wf2,
    const float* __restrict__ bf2v, float* __restrict__ out, int b_off)
{
  const int b = blockIdx.x, tid = threadIdx.x;
  __shared__ float cx[256];
  __shared__ float zb[128];
  __shared__ float red[4];
  cx[tid]       = ctx[(size_t)b*256 + tid];
  cx[128+tid]   = ctx[(size_t)b*256 + 128 + tid];
  __syncthreads();
  float y = bf1[tid];
  const float* wr = Wf1 + (size_t)tid*256;
  #pragma unroll 8
  for (int k=0; k<256; ++k) y += cx[k]*wr[k];
  float s = y;
  #pragma unroll
  for (int d=1; d<64; d<<=1) s += __shfl_xor(s, d);
  if ((tid&63)==0) red[tid>>6] = s;
  __syncthreads();
  float mu = (red[0]+red[1])*(1.f/128.f);
  float dv = y - mu;
  float q = dv*dv;
  #pragma unroll
  for (int d=1; d<64; d<<=1) q += __shfl_xor(q, d);
  if ((tid&63)==0) red[2+(tid>>6)] = q;
  __syncthreads();
  float var = (red[2]+red[3])*(1.f/128.f);
  float z = dv*rsqrtf(var + 1e-5f)*g2[tid] + b2[tid];
  z = fmaxf(z, 0.f);
  zb[tid] = z;
  __syncthreads();
  if (tid < 5){
    float o = bf2v[tid];
    const float* wp = Wf2 + (size_t)tid*128;
    for (int k=0; k<128; ++k) o += zb[k]*wp[k];
    out[(size_t)(b_off + b)*5 + tid] = o;
  }
}

extern "C" void kernel_launch(void* const* d_in, const int* in_sizes, int n_in,
                              void* d_out, int out_size, void* d_ws, size_t ws_size,
                              hipStream_t stream)
{
  const float* x    = (const float*)d_in[0];
  const float* ln_g = (const float*)d_in[1];
  const float* ln_b = (const float*)d_in[2];
  const float* Wih0 = (const float*)d_in[3];
  const float* Whh0 = (const float*)d_in[4];
  const float* bih0 = (const float*)d_in[5];
  const float* bhh0 = (const float*)d_in[6];
  const float* Wih1 = (const float*)d_in[7];
  const float* Whh1 = (const float*)d_in[8];
  const float* bih1 = (const float*)d_in[9];
  const float* bhh1 = (const float*)d_in[10];
  const float* Wa1  = (const float*)d_in[11];
  const float* ba1  = (const float*)d_in[12];
  const float* Wa2  = (const float*)d_in[13];
  const float* ba2  = (const float*)d_in[14];
  const float* Wf1  = (const float*)d_in[15];
  const float* bf1  = (const float*)d_in[16];
  const float* ln2g = (const float*)d_in[17];
  const float* ln2b = (const float*)d_in[18];
  const float* Wf2  = (const float*)d_in[19];
  const float* bf2  = (const float*)d_in[20];
  float* out = (float*)d_out;

  char* wsb = (char*)d_ws;
  const size_t HBf = (size_t)TT*1024*256*2;   // 134,217,728

  prep_wih1<<<128, 256, 0, stream>>>(Wih1);

  if (ws_size >= 2*HBf){
    // ---------- FULL: whole batch in one pass; scores/ctx alias dead h0 ----------
    uint16_t* h0 = (uint16_t*)wsb;
    uint16_t* h1 = (uint16_t*)(wsb + HBf);
    float* scoresP = (float*)wsb;
    float* ctxP    = (float*)(wsb + (size_t)1024*TT*4);

    lstm0_kernel<<<512, 512, 0, stream>>>(x, ln_g, ln_b, Wih0, Whh0, bih0, bhh0,
                                          h0, 256, 1024, 0);
    lstm1_kernel<<<512, 512, 0, stream>>>(h0, Whh1, bih1, bhh1, h1, 256, 1024);
    scores_kernel<<<TT*16, 256, 0, stream>>>(h1, Wa1, ba1, Wa2, ba2, scoresP, 16, 1024);
    ctx_kernel   <<<1024, 256, 0, stream>>>(h1, scoresP, ctxP, 1024);
    head_kernel  <<<1024, 128, 0, stream>>>(ctxP, Wf1, bf1, ln2g, ln2b, Wf2, bf2, out, 0);
  } else {
    // ---------- fallback: rounds of BR samples ----------
    int BR = 512;
    while (BR > 64){
      size_t HB = (size_t)TT*BR*256*2;
      if (2*HB + 2*((size_t)BR*256*4) <= ws_size) break;
      BR >>= 1;
    }
    const size_t HB = (size_t)TT*BR*256*2;
    uint16_t* h0 = (uint16_t*)wsb;
    uint16_t* h1 = (uint16_t*)(wsb + HB);
    float* scoresP = (float*)(wsb + 2*HB);
    float* ctxP    = (float*)(wsb + 2*HB + (size_t)BR*256*4);
    const int nb = BR/NS;

    for (int b_off = 0; b_off < 1024; b_off += BR){
      lstm0_kernel<<<2*nb, 512, 0, stream>>>(x, ln_g, ln_b, Wih0, Whh0, bih0, bhh0,
                                             h0, nb, BR, b_off);
      lstm1_kernel<<<2*nb, 512, 0, stream>>>(h0, Whh1, bih1, bhh1, h1, nb, BR);
      scores_kernel<<<TT*(BR/64), 256, 0, stream>>>(h1, Wa1, ba1, Wa2, ba2, scoresP,
                                                    BR/64, BR);
      ctx_kernel   <<<BR, 256, 0, stream>>>(h1, scoresP, ctxP, BR);
      head_kernel  <<<BR, 128, 0, stream>>>(ctxP, Wf1, bf1, ln2g, ln2b, Wf2, bf2,
                                            out, b_off);
    }
  }
}

// Round 7
// 1294.601 us; speedup vs baseline: 2.1002x; 1.5083x over previous
//
#include <hip/hip_runtime.h>
#include <stdint.h>

#define TT 256
#define NS 8
#define CH 8

typedef __attribute__((ext_vector_type(4))) float f32x4;
typedef __attribute__((ext_vector_type(8))) short s16x8;

#define DEV static __device__ __forceinline__

// prepped bf16 Wih1 fragments: [dir][ntg(32)][kt(8)][lane(64)][8]
__device__ uint16_t g_W1f[2*32*8*64*8];

DEV short f2bf(float f){
  union{float f; uint32_t u;} v; v.f = f;
  uint32_t r = v.u + 0x7fffu + ((v.u>>16)&1u);
  return (short)(r>>16);
}
DEV float bf2f(uint32_t u16){
  union{uint32_t u; float f;} v; v.u = u16<<16; return v.f;
}
DEV uint32_t pk2(float a, float b){
  return (uint32_t)(uint16_t)f2bf(a) | ((uint32_t)(uint16_t)f2bf(b)<<16);
}
DEV float sigm(float x){ return 1.f/(1.f + __expf(-x)); }
DEV float tanh_f(float x){ float e = __expf(2.f*x); return 1.f - 2.f/(e+1.f); }
DEV f32x4 MFMA(s16x8 a, s16x8 b, f32x4 c){
  return __builtin_amdgcn_mfma_f32_16x16x32_bf16(a, b, c, 0, 0, 0);
}
DEV s16x8 cvt8(const float* p){
  f32x4 a = *(const f32x4*)p;
  f32x4 b = *(const f32x4*)(p+4);
  s16x8 o;
  o[0]=f2bf(a[0]); o[1]=f2bf(a[1]); o[2]=f2bf(a[2]); o[3]=f2bf(a[3]);
  o[4]=f2bf(b[0]); o[5]=f2bf(b[1]); o[6]=f2bf(b[2]); o[7]=f2bf(b[3]);
  return o;
}
// barrier that drains LDS only (global stores/loads stay in flight)
DEV void bar_lds(){
  asm volatile("s_waitcnt lgkmcnt(0)" ::: "memory");
  __builtin_amdgcn_s_barrier();
}

// flush 4 steps x 8 rows x 128 cols of bf16 h from LDS (8KB region) to global.
DEV void flush4(const char* src, uint16_t* __restrict__ hdst, int t0,
                int dir, int BR, int bg, int tid){
  int row = tid >> 4, part = tid & 15;       // 32 rows x 16 parts
  int tp = t0 + (row >> 3), b = row & 7;
  int tg = dir ? (TT-1-tp) : tp;
  s16x8 v = *(const s16x8*)(src + row*256 + part*16);
  *(s16x8*)(hdst + ((size_t)tg*BR + bg*NS + b)*256 + dir*128 + part*8) = v;
}

// ---------------- Wih1 -> bf16 B-fragment layout ----------------
__global__ __launch_bounds__(256) void prep_wih1(const float* __restrict__ Wih1)
{
  int tid = blockIdx.x*256 + threadIdx.x;   // 32768 total
  int l = tid & 63, kt = (tid>>6)&7, ntg = (tid>>9)&31, dir = (tid>>14)&1;
  int lm = l&15, lk = l>>4;
  int n = ntg*16 + lm;
  s16x8 o = cvt8(Wih1 + ((size_t)(dir*512 + n))*256 + kt*32 + lk*8);
  *(s16x8*)(&g_W1f[(size_t)tid*8]) = o;
}

// ================= BiLSTM layer 0 (LN fused; 6 -> 128/dir), NS=8 =================
__global__ __launch_bounds__(512,1) void lstm0_kernel(
    const float* __restrict__ x, const float* __restrict__ lng,
    const float* __restrict__ lnb,
    const float* __restrict__ Wih0, const float* __restrict__ Whh0,
    const float* __restrict__ bih0, const float* __restrict__ bhh0,
    uint16_t* __restrict__ h0, int nb, int BR, int b_off)
{
  const int dir = blockIdx.x / nb, bg = blockIdx.x % nb;
  const int tid = threadIdx.x, w = tid>>6, l = tid&63;
  const int lm = l&15, lk = l>>4;
  const int gb = b_off + bg*NS;

  __shared__ short hbuf[2][2048];     // 8 KB, XOR(row<<4) swizzle
  __shared__ short xnbf[TT*NS*8];     // 32 KB: [t][r][8] bf16 (K=6 padded)
  __shared__ short houts[2][4096];    // 16 KB: 2 regions x 4 steps x 8 rows x 128

  for (int i=tid; i<4096; i+=512) ((short*)hbuf)[i] = 0;

  // LN fused staging
  #pragma unroll
  for (int it=0; it<4; ++it){
    int pr = it*512 + tid;
    int r = pr >> 8, t = pr & 255;
    const float* px = x + ((size_t)(gb+r)*TT + t)*6;
    float v[6]; float mu=0.f, var=0.f;
    #pragma unroll
    for (int d=0; d<6; ++d){ v[d]=px[d]; mu+=v[d]; }
    mu *= (1.f/6.f);
    #pragma unroll
    for (int d=0; d<6; ++d){ float dd=v[d]-mu; var+=dd*dd; }
    float rs = rsqrtf(var*(1.f/6.f) + 1e-5f);
    s16x8 vv;
    #pragma unroll
    for (int d=0; d<6; ++d) vv[d] = f2bf((v[d]-mu)*rs*lng[d] + lnb[d]);
    vv[6]=0; vv[7]=0;
    *(s16x8*)&xnbf[(t*NS + r)*8] = vv;
  }

  const int c = w*16 + lm;
  s16x8 bw[4][4], bx[4];
  float biasc[4];
  #pragma unroll
  for (int G=0; G<4; ++G){
    const int n = G*128 + c;
    biasc[G] = bih0[dir*512+n] + bhh0[dir*512+n];
    #pragma unroll
    for (int kt=0; kt<4; ++kt)
      bw[G][kt] = cvt8(Whh0 + ((size_t)(dir*512+n))*128 + kt*32 + lk*8);
    s16x8 tx;
    #pragma unroll
    for (int j=0; j<8; ++j){
      int k = lk*8 + j;
      tx[j] = (k<6) ? f2bf(Wih0[(size_t)(dir*512+n)*6 + k]) : (short)0;
    }
    bx[G] = tx;
  }

  const int r0 = ((l>>4)&1)*4 + ((l<32)?0:2);
  float cst[2] = {0.f, 0.f};
  __syncthreads();

  for (int t=0; t<TT; ++t){
    const int tt = dir ? (TT-1-t) : t;
    const int rd = t & 1;
    s16x8 ah[4];
    #pragma unroll
    for (int kt=0; kt<4; ++kt){
      int off = rd*4096 + lm*256 + ((kt*64 + lk*16) ^ (lm<<4));
      ah[kt] = *(const s16x8*)((const char*)hbuf + off);
    }
    s16x8 ax = {0,0,0,0,0,0,0,0};
    if (l < 8) ax = *(const s16x8*)&xnbf[(tt*NS + l)*8];

    f32x4 acc[4];
    #pragma unroll
    for (int G=0; G<4; ++G){
      f32x4 a = {0.f,0.f,0.f,0.f};
      #pragma unroll
      for (int kt=0; kt<4; ++kt) a = MFMA(ah[kt], bw[G][kt], a);
      a = MFMA(ax, bx[G], a);
      acc[G] = a;
    }

    float g0[4], g1[4];
    #pragma unroll
    for (int G=0; G<4; ++G){
      float o2 = __shfl(acc[G][2], l & 31);
      float o3 = __shfl(acc[G][3], l & 31);
      g0[G] = ((l<32) ? acc[G][0] : o2) + biasc[G];
      g1[G] = ((l<32) ? acc[G][1] : o3) + biasc[G];
    }
    float hv[2];
    {
      float cc = sigm(g0[1])*cst[0] + sigm(g0[0])*tanh_f(g0[2]);
      cst[0] = cc; hv[0] = sigm(g0[3])*tanh_f(cc);
      cc = sigm(g1[1])*cst[1] + sigm(g1[0])*tanh_f(g1[2]);
      cst[1] = cc; hv[1] = sigm(g1[3])*tanh_f(cc);
    }

    #pragma unroll
    for (int q=0; q<2; ++q){
      int r = r0 + q;
      short hb = f2bf(hv[q]);
      *(short*)((char*)hbuf + (rd^1)*4096 + r*256 + ((c*2) ^ (r<<4))) = hb;
      *(short*)((char*)houts + ((t>>2)&1)*8192 + ((t&3)*NS + r)*256 + c*2) = hb;
    }
    bar_lds();
    if ((t&3) == 3)
      flush4((const char*)houts + ((t>>2)&1)*8192, h0, t-3, dir, BR, bg, tid);
  }
}

// ============ BiLSTM layer 1 (256 -> 128/dir), fused xp, NS=8, CH=8 ============
__global__ __launch_bounds__(512,1) void lstm1_kernel(
    const uint16_t* __restrict__ h0,
    const float* __restrict__ Whh1, const float* __restrict__ bih1,
    const float* __restrict__ bhh1, uint16_t* __restrict__ h1,
    int nb, int BR)
{
  const int dir = blockIdx.x / nb, bg = blockIdx.x % nb;
  const int tid = threadIdx.x, w = tid>>6, l = tid&63;
  const int lm = l&15, lk = l>>4;

  __shared__ short hbuf[2][2048];     // 8 KB
  __shared__ short abuf[2][16384];    // 64 KB: 64 rows (8 steps x 8 samples) x 256, dbuf

  for (int i=tid; i<4096; i+=512) ((short*)hbuf)[i] = 0;

  const int c = w*16 + lm;
  s16x8 bw[4][4];
  float biasv[4];
  #pragma unroll
  for (int G=0; G<4; ++G){
    const int n = G*128 + c;
    biasv[G] = bih1[dir*512+n] + bhh1[dir*512+n];
    #pragma unroll
    for (int kt=0; kt<4; ++kt)
      bw[G][kt] = cvt8(Whh1 + ((size_t)(dir*512+n))*128 + kt*32 + lk*8);
  }

  const int r0 = ((l>>4)&1)*4 + ((l<32)?0:2);
  float cst[2] = {0.f,0.f};
  uint32_t xpk[4][4][2];   // [G][mt][word]: xp rows mt*16 + lk*4 + {0..3}
  s16x8 vst[4];

  // prologue: stage chunk 0 (rows = s*8 + b)
  #pragma unroll
  for (int it=0; it<4; ++it){
    int sid = it*512 + tid, row = sid>>5, sl = sid&31, s = row>>3, b = row&7;
    int tg = dir ? (TT-1-s) : s;
    vst[it] = *(const s16x8*)(h0 + ((size_t)tg*BR + bg*NS + b)*256 + sl*8);
  }
  #pragma unroll
  for (int it=0; it<4; ++it){
    int sid = it*512 + tid, row = sid>>5, sl = sid&31;
    *(s16x8*)((char*)abuf + row*512 + ((sl ^ (row&15))<<4)) = vst[it];
  }
  __syncthreads();

  for (int ch=0; ch<TT/CH; ++ch){
    const int cur = ch & 1;
    const char* ab = (const char*)abuf + cur*32768;

    // issue next chunk's loads early (land during phase A)
    if (ch < TT/CH-1){
      #pragma unroll
      for (int it=0; it<4; ++it){
        int sid = it*512 + tid, row = sid>>5, sl = sid&31, s = row>>3, b = row&7;
        int ts = (ch+1)*CH + s;
        int tg = dir ? (TT-1-ts) : ts;
        vst[it] = *(const s16x8*)(h0 + ((size_t)tg*BR + bg*NS + b)*256 + sl*8);
      }
    }

    // ---- phase A: xp for CH steps (G-outer, prepped bf16 weight fragments) ----
    #pragma unroll
    for (int G=0; G<4; ++G){
      f32x4 acc[4];
      #pragma unroll
      for (int mt=0; mt<4; ++mt) acc[mt] = (f32x4){biasv[G],biasv[G],biasv[G],biasv[G]};
      #pragma unroll
      for (int kt=0; kt<8; ++kt){
        s16x8 bfr = *(const s16x8*)(&g_W1f[(((size_t)(dir*32 + G*8 + w)*8 + kt)*64 + l)*8]);
        #pragma unroll
        for (int mt=0; mt<4; ++mt){
          int row = mt*16 + lm;
          s16x8 afr = *(const s16x8*)(ab + row*512 + (((kt*4+lk) ^ (row&15))<<4));
          acc[mt] = MFMA(afr, bfr, acc[mt]);
        }
      }
      #pragma unroll
      for (int mt=0; mt<4; ++mt){
        xpk[G][mt][0] = pk2(acc[mt][0], acc[mt][1]);
        xpk[G][mt][1] = pk2(acc[mt][2], acc[mt][3]);
      }
    }

    // write staged regs -> other abuf (its readers finished last chunk)
    if (ch < TT/CH-1){
      char* ab2 = (char*)abuf + (cur^1)*32768;
      #pragma unroll
      for (int it=0; it<4; ++it){
        int sid = it*512 + tid, row = sid>>5, sl = sid&31;
        *(s16x8*)(ab2 + row*512 + ((sl ^ (row&15))<<4)) = vst[it];
      }
    }
    bar_lds();   // all phase-A reads of ab done -> ab reusable as houts

    // ---- phase B: CH recurrent steps; houts reuses abuf[cur] ----
    #pragma unroll
    for (int s=0; s<CH; ++s){
      const int gs = ch*CH + s;
      const int rd = gs & 1;
      const int mt = s >> 1;
      // holder of xp[s][b=lk*4+j][c]: lane ((s&1)*2 + lk)*16 + lm
      const int src = ((((s&1)<<1) + lk)*16 + lm) & 63;

      f32x4 acc4[4];
      #pragma unroll
      for (int G=0; G<4; ++G){
        uint32_t p0 = (uint32_t)__shfl((int)xpk[G][mt][0], src);
        uint32_t p1 = (uint32_t)__shfl((int)xpk[G][mt][1], src);
        acc4[G] = (f32x4){bf2f(p0&0xffffu), bf2f(p0>>16), bf2f(p1&0xffffu), bf2f(p1>>16)};
      }

      s16x8 ah[4];
      #pragma unroll
      for (int kt=0; kt<4; ++kt){
        int off = rd*4096 + lm*256 + ((kt*64 + lk*16) ^ (lm<<4));
        ah[kt] = *(const s16x8*)((const char*)hbuf + off);
      }
      #pragma unroll
      for (int G=0; G<4; ++G){
        #pragma unroll
        for (int kt=0; kt<4; ++kt)
          acc4[G] = MFMA(ah[kt], bw[G][kt], acc4[G]);
      }

      float g0[4], g1[4];
      #pragma unroll
      for (int G=0; G<4; ++G){
        float o2 = __shfl(acc4[G][2], l & 31);
        float o3 = __shfl(acc4[G][3], l & 31);
        g0[G] = (l<32) ? acc4[G][0] : o2;
        g1[G] = (l<32) ? acc4[G][1] : o3;
      }
      float hv[2];
      float cc = sigm(g0[1])*cst[0] + sigm(g0[0])*tanh_f(g0[2]);
      cst[0] = cc; hv[0] = sigm(g0[3])*tanh_f(cc);
      cc = sigm(g1[1])*cst[1] + sigm(g1[0])*tanh_f(g1[2]);
      cst[1] = cc; hv[1] = sigm(g1[3])*tanh_f(cc);

      #pragma unroll
      for (int q=0; q<2; ++q){
        int r = r0 + q;
        short hb = f2bf(hv[q]);
        *(short*)((char*)hbuf + (rd^1)*4096 + r*256 + ((c*2) ^ (r<<4))) = hb;
        *(short*)((char*)ab + ((s>>2)&1)*8192 + ((s&3)*NS + r)*256 + c*2) = hb;
      }
      bar_lds();
      if ((s&3) == 3)
        flush4(ab + ((s>>2)&1)*8192, h1, ch*CH + (s-3), dir, BR, bg, tid);
    }
    bar_lds();   // protect last flush reads before next chunk's staging writes
  }
}

// ================= attention scores =================
__global__ __launch_bounds__(256,2) void scores_kernel(
    const uint16_t* __restrict__ h1, const float* __restrict__ Wa1,
    const float* __restrict__ ba1, const float* __restrict__ Wa2,
    const float* __restrict__ ba2, float* __restrict__ scores,
    int nbb, int BR)
{
  const int bx = blockIdx.x;
  const int t = bx / nbb, bb = (bx - t*nbb) * 64;
  const int tid = threadIdx.x, w = tid>>6, l = tid&63;
  const int lm = l&15, lk = l>>4;
  __shared__ short abuf[64*256];
  __shared__ float scred[4][64];

  #pragma unroll
  for (int it=0; it<8; ++it){
    int sid = it*256 + tid, row = sid>>5, sl = sid&31;
    s16x8 v = *(const s16x8*)(h1 + ((size_t)t*BR + bb + row)*256 + sl*8);
    *(s16x8*)((char*)abuf + row*512 + ((sl ^ (row&15))<<4)) = v;
  }

  s16x8 bwa[2][8]; float b1v[2], wa2v[2];
  #pragma unroll
  for (int nt=0; nt<2; ++nt){
    int n = w*32 + nt*16 + lm;
    b1v[nt] = ba1[n]; wa2v[nt] = Wa2[n];
    #pragma unroll
    for (int kt=0; kt<8; ++kt)
      bwa[nt][kt] = cvt8(Wa1 + (size_t)n*256 + kt*32 + lk*8);
  }
  __syncthreads();

  #pragma unroll
  for (int mt=0; mt<4; ++mt){
    f32x4 a0 = {b1v[0],b1v[0],b1v[0],b1v[0]};
    f32x4 a1 = {b1v[1],b1v[1],b1v[1],b1v[1]};
    #pragma unroll
    for (int kt=0; kt<8; ++kt){
      int row = mt*16 + lm;
      s16x8 af = *(const s16x8*)((const char*)abuf + row*512 + (((kt*4+lk) ^ (row&15))<<4));
      a0 = MFMA(af, bwa[0][kt], a0);
      a1 = MFMA(af, bwa[1][kt], a1);
    }
    #pragma unroll
    for (int j=0; j<4; ++j){
      float pj = tanh_f(a0[j])*wa2v[0] + tanh_f(a1[j])*wa2v[1];
      #pragma unroll
      for (int m=1; m<16; m<<=1) pj += __shfl_xor(pj, m);
      if (lm == 0) scred[w][mt*16 + lk*4 + j] = pj;
    }
  }
  __syncthreads();
  if (tid < 64){
    float s = scred[0][tid]+scred[1][tid]+scred[2][tid]+scred[3][tid] + ba2[0];
    scores[(size_t)(bb+tid)*TT + t] = s;
  }
}

// ================= softmax over T + context =================
__global__ __launch_bounds__(256,2) void ctx_kernel(
    const uint16_t* __restrict__ h1, const float* __restrict__ scores,
    float* __restrict__ context, int BR)
{
  const int b = blockIdx.x, tid = threadIdx.x;
  __shared__ float at[TT];
  __shared__ float red[8];
  float sc = scores[(size_t)b*TT + tid];
  float m = sc;
  #pragma unroll
  for (int d=1; d<64; d<<=1) m = fmaxf(m, __shfl_xor(m, d));
  if ((tid&63)==0) red[tid>>6] = m;
  __syncthreads();
  m = fmaxf(fmaxf(red[0],red[1]), fmaxf(red[2],red[3]));
  float e = __expf(sc - m);
  float s = e;
  #pragma unroll
  for (int d=1; d<64; d<<=1) s += __shfl_xor(s, d);
  if ((tid&63)==0) red[4+(tid>>6)] = s;
  __syncthreads();
  s = red[4]+red[5]+red[6]+red[7];
  at[tid] = e / s;
  __syncthreads();

  float acc = 0.f;
  const uint16_t* hp = h1 + (size_t)b*256 + tid;
  #pragma unroll 4
  for (int t2=0; t2<TT; ++t2) acc += at[t2] * bf2f(hp[(size_t)t2*BR*256]);
  context[(size_t)b*256 + tid] = acc;
}

// ================= head =================
__global__ __launch_bounds__(128,2) void head_kernel(
    const float* __restrict__ ctx, const float* __restrict__ Wf1,
    const float* __restrict__ bf1, const float* __restrict__ g2,
    const float* __restrict__ b2, const float* __restrict__ Wf2,
    const float* __restrict__ bf2v, float* __restrict__ out, int b_off)
{
  const int b = blockIdx.x, tid = threadIdx.x;
  __shared__ float cx[256];
  __shared__ float zb[128];
  __shared__ float red[4];
  cx[tid]       = ctx[(size_t)b*256 + tid];
  cx[128+tid]   = ctx[(size_t)b*256 + 128 + tid];
  __syncthreads();
  float y = bf1[tid];
  const float* wr = Wf1 + (size_t)tid*256;
  #pragma unroll 8
  for (int k=0; k<256; ++k) y += cx[k]*wr[k];
  float s = y;
  #pragma unroll
  for (int d=1; d<64; d<<=1) s += __shfl_xor(s, d);
  if ((tid&63)==0) red[tid>>6] = s;
  __syncthreads();
  float mu = (red[0]+red[1])*(1.f/128.f);
  float dv = y - mu;
  float q = dv*dv;
  #pragma unroll
  for (int d=1; d<64; d<<=1) q += __shfl_xor(q, d);
  if ((tid&63)==0) red[2+(tid>>6)] = q;
  __syncthreads();
  float var = (red[2]+red[3])*(1.f/128.f);
  float z = dv*rsqrtf(var + 1e-5f)*g2[tid] + b2[tid];
  z = fmaxf(z, 0.f);
  zb[tid] = z;
  __syncthreads();
  if (tid < 5){
    float o = bf2v[tid];
    const float* wp = Wf2 + (size_t)tid*128;
    for (int k=0; k<128; ++k) o += zb[k]*wp[k];
    out[(size_t)(b_off + b)*5 + tid] = o;
  }
}

extern "C" void kernel_launch(void* const* d_in, const int* in_sizes, int n_in,
                              void* d_out, int out_size, void* d_ws, size_t ws_size,
                              hipStream_t stream)
{
  const float* x    = (const float*)d_in[0];
  const float* ln_g = (const float*)d_in[1];
  const float* ln_b = (const float*)d_in[2];
  const float* Wih0 = (const float*)d_in[3];
  const float* Whh0 = (const float*)d_in[4];
  const float* bih0 = (const float*)d_in[5];
  const float* bhh0 = (const float*)d_in[6];
  const float* Wih1 = (const float*)d_in[7];
  const float* Whh1 = (const float*)d_in[8];
  const float* bih1 = (const float*)d_in[9];
  const float* bhh1 = (const float*)d_in[10];
  const float* Wa1  = (const float*)d_in[11];
  const float* ba1  = (const float*)d_in[12];
  const float* Wa2  = (const float*)d_in[13];
  const float* ba2  = (const float*)d_in[14];
  const float* Wf1  = (const float*)d_in[15];
  const float* bf1  = (const float*)d_in[16];
  const float* ln2g = (const float*)d_in[17];
  const float* ln2b = (const float*)d_in[18];
  const float* Wf2  = (const float*)d_in[19];
  const float* bf2  = (const float*)d_in[20];
  float* out = (float*)d_out;

  char* wsb = (char*)d_ws;
  const size_t HBf = (size_t)TT*1024*256*2;   // 134,217,728

  prep_wih1<<<128, 256, 0, stream>>>(Wih1);

  if (ws_size >= 2*HBf){
    // ---------- FULL: whole batch in one pass; scores/ctx alias dead h0 ----------
    uint16_t* h0 = (uint16_t*)wsb;
    uint16_t* h1 = (uint16_t*)(wsb + HBf);
    float* scoresP = (float*)wsb;
    float* ctxP    = (float*)(wsb + (size_t)1024*TT*4);

    lstm0_kernel<<<256, 512, 0, stream>>>(x, ln_g, ln_b, Wih0, Whh0, bih0, bhh0,
                                          h0, 128, 1024, 0);
    lstm1_kernel<<<256, 512, 0, stream>>>(h0, Whh1, bih1, bhh1, h1, 128, 1024);
    scores_kernel<<<TT*16, 256, 0, stream>>>(h1, Wa1, ba1, Wa2, ba2, scoresP, 16, 1024);
    ctx_kernel   <<<1024, 256, 0, stream>>>(h1, scoresP, ctxP, 1024);
    head_kernel  <<<1024, 128, 0, stream>>>(ctxP, Wf1, bf1, ln2g, ln2b, Wf2, bf2, out, 0);
  } else {
    // ---------- fallback: rounds of BR samples ----------
    int BR = 512;
    while (BR > 64){
      size_t HB = (size_t)TT*BR*256*2;
      if (2*HB + 2*((size_t)BR*256*4) <= ws_size) break;
      BR >>= 1;
    }
    const size_t HB = (size_t)TT*BR*256*2;
    uint16_t* h0 = (uint16_t*)wsb;
    uint16_t* h1 = (uint16_t*)(wsb + HB);
    float* scoresP = (float*)(wsb + 2*HB);
    float* ctxP    = (float*)(wsb + 2*HB + (size_t)BR*256*4);
    const int nb = BR/NS;

    for (int b_off = 0; b_off < 1024; b_off += BR){
      lstm0_kernel<<<2*nb, 512, 0, stream>>>(x, ln_g, ln_b, Wih0, Whh0, bih0, bhh0,
                                             h0, nb, BR, b_off);
      lstm1_kernel<<<2*nb, 512, 0, stream>>>(h0, Whh1, bih1, bhh1, h1, nb, BR);
      scores_kernel<<<TT*(BR/64), 256, 0, stream>>>(h1, Wa1, ba1, Wa2, ba2, scoresP,
                                                    BR/64, BR);
      ctx_kernel   <<<BR, 256, 0, stream>>>(h1, scoresP, ctxP, BR);
      head_kernel  <<<BR, 128, 0, stream>>>(ctxP, Wf1, bf1, ln2g, ln2b, Wf2, bf2,
                                            out, b_off);
    }
  }
}

// Round 8
// 938.906 us; speedup vs baseline: 2.8958x; 1.3788x over previous
//
#include <hip/hip_runtime.h>
#include <stdint.h>

#define TT 256
#define NS 8
#define CH 8

typedef __attribute__((ext_vector_type(4))) float f32x4;
typedef __attribute__((ext_vector_type(8))) short s16x8;
typedef __attribute__((ext_vector_type(2))) unsigned int u32x2;

#define DEV static __device__ __forceinline__

// prepped bf16 Wih1 fragments: [dir][ntg(32)][kt(8)][lane(64)][8]
__device__ uint16_t g_W1f[2*32*8*64*8];

DEV short f2bf(float f){
  union{float f; uint32_t u;} v; v.f = f;
  uint32_t r = v.u + 0x7fffu + ((v.u>>16)&1u);
  return (short)(r>>16);
}
DEV float bf2f(uint32_t u16){
  union{uint32_t u; float f;} v; v.u = u16<<16; return v.f;
}
DEV uint32_t pk2(float a, float b){
  return (uint32_t)(uint16_t)f2bf(a) | ((uint32_t)(uint16_t)f2bf(b)<<16);
}
DEV float sigm(float x){ return 1.f/(1.f + __expf(-x)); }
DEV float tanh_f(float x){ float e = __expf(2.f*x); return 1.f - 2.f/(e+1.f); }
DEV f32x4 MFMA(s16x8 a, s16x8 b, f32x4 c){
  return __builtin_amdgcn_mfma_f32_16x16x32_bf16(a, b, c, 0, 0, 0);
}
DEV s16x8 cvt8(const float* p){
  f32x4 a = *(const f32x4*)p;
  f32x4 b = *(const f32x4*)(p+4);
  s16x8 o;
  o[0]=f2bf(a[0]); o[1]=f2bf(a[1]); o[2]=f2bf(a[2]); o[3]=f2bf(a[3]);
  o[4]=f2bf(b[0]); o[5]=f2bf(b[1]); o[6]=f2bf(b[2]); o[7]=f2bf(b[3]);
  return o;
}
// barrier that drains LDS only (global stores/loads stay in flight)
DEV void bar_lds(){
  asm volatile("s_waitcnt lgkmcnt(0)" ::: "memory");
  __builtin_amdgcn_s_barrier();
}

// flush 4 steps x 8 rows x 128 cols of bf16 h from LDS (8KB region, col-swizzled).
DEV void flush4(const char* src, uint16_t* __restrict__ hdst, int t0,
                int dir, int BR, int bg, int tid){
  int row = tid >> 4, part = tid & 15;       // 32 rows x 16 parts
  int tp = t0 + (row >> 3), b = row & 7;
  int tg = dir ? (TT-1-tp) : tp;
  s16x8 v = *(const s16x8*)(src + row*256 + ((part ^ (row&7))<<4));
  *(s16x8*)(hdst + ((size_t)tg*BR + bg*NS + b)*256 + dir*128 + part*8) = v;
}

// ---------------- Wih1 -> bf16 B-fragment layout ----------------
__global__ __launch_bounds__(256) void prep_wih1(const float* __restrict__ Wih1)
{
  int tid = blockIdx.x*256 + threadIdx.x;   // 32768 total
  int l = tid & 63, kt = (tid>>6)&7, ntg = (tid>>9)&31, dir = (tid>>14)&1;
  int lm = l&15, lk = l>>4;
  int n = ntg*16 + lm;
  s16x8 o = cvt8(Wih1 + ((size_t)(dir*512 + n))*256 + kt*32 + lk*8);
  *(s16x8*)(&g_W1f[(size_t)tid*8]) = o;
}

// ================= BiLSTM layer 0 (LN fused; 6 -> 128/dir), NS=8 =================
__global__ __launch_bounds__(512,2) void lstm0_kernel(
    const float* __restrict__ x, const float* __restrict__ lng,
    const float* __restrict__ lnb,
    const float* __restrict__ Wih0, const float* __restrict__ Whh0,
    const float* __restrict__ bih0, const float* __restrict__ bhh0,
    uint16_t* __restrict__ h0, int nb, int BR, int b_off)
{
  const int dir = blockIdx.x / nb, bg = blockIdx.x % nb;
  const int tid = threadIdx.x, w = tid>>6, l = tid&63;
  const int lm = l&15, lk = l>>4;
  const int gb = b_off + bg*NS;

  __shared__ short hbuf[2][2048];     // 8 KB, XOR(row<<4) swizzle
  __shared__ short xnbf[TT*NS*8];     // 32 KB: [t][r][8] bf16 (K=6 padded)
  __shared__ short houts[2][4096];    // 16 KB: 2 regions x 4 steps x 8 rows x 128
  __shared__ short bxs[8*4*64*8];     // 32 KB: input-proj fragments per (w,G,l)

  for (int i=tid; i<4096; i+=512) ((short*)hbuf)[i] = 0;

  // LN fused staging
  #pragma unroll
  for (int it=0; it<4; ++it){
    int pr = it*512 + tid;
    int r = pr >> 8, t = pr & 255;
    const float* px = x + ((size_t)(gb+r)*TT + t)*6;
    float v[6]; float mu=0.f, var=0.f;
    #pragma unroll
    for (int d=0; d<6; ++d){ v[d]=px[d]; mu+=v[d]; }
    mu *= (1.f/6.f);
    #pragma unroll
    for (int d=0; d<6; ++d){ float dd=v[d]-mu; var+=dd*dd; }
    float rs = rsqrtf(var*(1.f/6.f) + 1e-5f);
    s16x8 vv;
    #pragma unroll
    for (int d=0; d<6; ++d) vv[d] = f2bf((v[d]-mu)*rs*lng[d] + lnb[d]);
    vv[6]=0; vv[7]=0;
    *(s16x8*)&xnbf[(t*NS + r)*8] = vv;
  }

  const int c = w*16 + lm;
  s16x8 bw[4][4];
  float biasc[4];
  #pragma unroll
  for (int G=0; G<4; ++G){
    const int n = G*128 + c;
    biasc[G] = bih0[dir*512+n] + bhh0[dir*512+n];
    #pragma unroll
    for (int kt=0; kt<4; ++kt)
      bw[G][kt] = cvt8(Whh0 + ((size_t)(dir*512+n))*128 + kt*32 + lk*8);
    s16x8 tx;
    #pragma unroll
    for (int j=0; j<8; ++j){
      int k = lk*8 + j;
      tx[j] = (k<6) ? f2bf(Wih0[(size_t)(dir*512+n)*6 + k]) : (short)0;
    }
    *(s16x8*)&bxs[((w*4+G)*64 + l)*8] = tx;   // park in LDS (saves 16 VGPRs)
  }

  const int r0 = ((l>>4)&1)*4 + ((l<32)?0:2);
  float cst[2] = {0.f, 0.f};
  __syncthreads();

  for (int t=0; t<TT; ++t){
    const int tt = dir ? (TT-1-t) : t;
    const int rd = t & 1;
    s16x8 ah[4];
    #pragma unroll
    for (int kt=0; kt<4; ++kt){
      int off = rd*4096 + lm*256 + ((kt*64 + lk*16) ^ (lm<<4));
      ah[kt] = *(const s16x8*)((const char*)hbuf + off);
    }
    s16x8 ax = {0,0,0,0,0,0,0,0};
    if (l < 8) ax = *(const s16x8*)&xnbf[(tt*NS + l)*8];

    f32x4 acc[4];
    #pragma unroll
    for (int G=0; G<4; ++G){
      f32x4 a = {0.f,0.f,0.f,0.f};
      #pragma unroll
      for (int kt=0; kt<4; ++kt) a = MFMA(ah[kt], bw[G][kt], a);
      s16x8 bx = *(const s16x8*)&bxs[((w*4+G)*64 + l)*8];
      a = MFMA(ax, bx, a);
      acc[G] = a;
    }

    float g0[4], g1[4];
    #pragma unroll
    for (int G=0; G<4; ++G){
      float o2 = __shfl(acc[G][2], l & 31);
      float o3 = __shfl(acc[G][3], l & 31);
      g0[G] = ((l<32) ? acc[G][0] : o2) + biasc[G];
      g1[G] = ((l<32) ? acc[G][1] : o3) + biasc[G];
    }
    float hv[2];
    {
      float cc = sigm(g0[1])*cst[0] + sigm(g0[0])*tanh_f(g0[2]);
      cst[0] = cc; hv[0] = sigm(g0[3])*tanh_f(cc);
      cc = sigm(g1[1])*cst[1] + sigm(g1[0])*tanh_f(g1[2]);
      cst[1] = cc; hv[1] = sigm(g1[3])*tanh_f(cc);
    }

    #pragma unroll
    for (int q=0; q<2; ++q){
      int r = r0 + q;
      short hb = f2bf(hv[q]);
      *(short*)((char*)hbuf + (rd^1)*4096 + r*256 + ((c*2) ^ (r<<4))) = hb;
      *(short*)((char*)houts + ((t>>2)&1)*8192 + ((t&3)*NS + r)*256
                + ((c*2) ^ (r<<4))) = hb;
    }
    bar_lds();
    if ((t&3) == 3)
      flush4((const char*)houts + ((t>>2)&1)*8192, h0, t-3, dir, BR, bg, tid);
  }
}

// ============ BiLSTM layer 1 (256 -> 128/dir), fused xp, NS=8, CH=8 ============
__global__ __launch_bounds__(512,2) void lstm1_kernel(
    const uint16_t* __restrict__ h0,
    const float* __restrict__ Whh1, const float* __restrict__ bih1,
    const float* __restrict__ bhh1, uint16_t* __restrict__ h1,
    int nb, int BR)
{
  const int dir = blockIdx.x / nb, bg = blockIdx.x % nb;
  const int tid = threadIdx.x, w = tid>>6, l = tid&63;
  const int lm = l&15, lk = l>>4;

  __shared__ short hbuf[2][2048];     // 8 KB
  __shared__ short abuf[2][16384];    // 64 KB: 64 rows (8 steps x 8 samples) x 256, dbuf
  __shared__ u32x2 xpbuf[8192];       // 64 KB: [w][G][mt][lane] packed-bf16 xp

  for (int i=tid; i<4096; i+=512) ((short*)hbuf)[i] = 0;

  const int c = w*16 + lm;
  s16x8 bw[4][4];
  float biasv[4];
  #pragma unroll
  for (int G=0; G<4; ++G){
    const int n = G*128 + c;
    biasv[G] = bih1[dir*512+n] + bhh1[dir*512+n];
    #pragma unroll
    for (int kt=0; kt<4; ++kt)
      bw[G][kt] = cvt8(Whh1 + ((size_t)(dir*512+n))*128 + kt*32 + lk*8);
  }

  const int r0 = ((l>>4)&1)*4 + ((l<32)?0:2);
  float cst[2] = {0.f,0.f};
  s16x8 vst[4];

  // prologue: stage chunk 0 (rows = s*8 + b)
  #pragma unroll
  for (int it=0; it<4; ++it){
    int sid = it*512 + tid, row = sid>>5, sl = sid&31, s = row>>3, b = row&7;
    int tg = dir ? (TT-1-s) : s;
    vst[it] = *(const s16x8*)(h0 + ((size_t)tg*BR + bg*NS + b)*256 + sl*8);
  }
  #pragma unroll
  for (int it=0; it<4; ++it){
    int sid = it*512 + tid, row = sid>>5, sl = sid&31;
    *(s16x8*)((char*)abuf + row*512 + ((sl ^ (row&15))<<4)) = vst[it];
  }
  __syncthreads();

  for (int ch=0; ch<TT/CH; ++ch){
    const int cur = ch & 1;
    const char* ab = (const char*)abuf + cur*32768;

    // issue next chunk's loads early (land during phase A)
    if (ch < TT/CH-1){
      #pragma unroll
      for (int it=0; it<4; ++it){
        int sid = it*512 + tid, row = sid>>5, sl = sid&31, s = row>>3, b = row&7;
        int ts = (ch+1)*CH + s;
        int tg = dir ? (TT-1-ts) : ts;
        vst[it] = *(const s16x8*)(h0 + ((size_t)tg*BR + bg*NS + b)*256 + sl*8);
      }
    }

    // ---- phase A: xp for CH steps -> LDS (frees 32 VGPRs vs reg-resident) ----
    #pragma unroll
    for (int G=0; G<4; ++G){
      f32x4 acc[4];
      #pragma unroll
      for (int mt=0; mt<4; ++mt) acc[mt] = (f32x4){biasv[G],biasv[G],biasv[G],biasv[G]};
      #pragma unroll
      for (int kt=0; kt<8; ++kt){
        s16x8 bfr = *(const s16x8*)(&g_W1f[(((size_t)(dir*32 + G*8 + w)*8 + kt)*64 + l)*8]);
        #pragma unroll
        for (int mt=0; mt<4; ++mt){
          int row = mt*16 + lm;
          s16x8 afr = *(const s16x8*)(ab + row*512 + (((kt*4+lk) ^ (row&15))<<4));
          acc[mt] = MFMA(afr, bfr, acc[mt]);
        }
      }
      #pragma unroll
      for (int mt=0; mt<4; ++mt){
        u32x2 pw;
        pw[0] = pk2(acc[mt][0], acc[mt][1]);
        pw[1] = pk2(acc[mt][2], acc[mt][3]);
        xpbuf[((w*4+G)*4+mt)*64 + l] = pw;
      }
    }

    // write staged regs -> other abuf (its readers finished last chunk)
    if (ch < TT/CH-1){
      char* ab2 = (char*)abuf + (cur^1)*32768;
      #pragma unroll
      for (int it=0; it<4; ++it){
        int sid = it*512 + tid, row = sid>>5, sl = sid&31;
        *(s16x8*)(ab2 + row*512 + ((sl ^ (row&15))<<4)) = vst[it];
      }
    }
    bar_lds();   // phase-A reads of ab done -> ab reusable as houts

    // ---- phase B: CH recurrent steps; houts reuses abuf[cur] ----
    #pragma unroll
    for (int s=0; s<CH; ++s){
      const int gs = ch*CH + s;
      const int rd = gs & 1;
      // holder lane of xp rows (s*8 + lk*4 + j): ((s&1)*2+lk)*16 + lm
      const int lane2 = ((((s&1)<<1) + lk)<<4) + lm;

      f32x4 acc4[4];
      #pragma unroll
      for (int G=0; G<4; ++G){
        u32x2 pw = xpbuf[((w*4+G)*4 + (s>>1))*64 + lane2];
        acc4[G] = (f32x4){bf2f(pw[0]&0xffffu), bf2f(pw[0]>>16),
                          bf2f(pw[1]&0xffffu), bf2f(pw[1]>>16)};
      }

      s16x8 ah[4];
      #pragma unroll
      for (int kt=0; kt<4; ++kt){
        int off = rd*4096 + lm*256 + ((kt*64 + lk*16) ^ (lm<<4));
        ah[kt] = *(const s16x8*)((const char*)hbuf + off);
      }
      #pragma unroll
      for (int G=0; G<4; ++G){
        #pragma unroll
        for (int kt=0; kt<4; ++kt)
          acc4[G] = MFMA(ah[kt], bw[G][kt], acc4[G]);
      }

      float g0[4], g1[4];
      #pragma unroll
      for (int G=0; G<4; ++G){
        float o2 = __shfl(acc4[G][2], l & 31);
        float o3 = __shfl(acc4[G][3], l & 31);
        g0[G] = (l<32) ? acc4[G][0] : o2;
        g1[G] = (l<32) ? acc4[G][1] : o3;
      }
      float hv[2];
      float cc = sigm(g0[1])*cst[0] + sigm(g0[0])*tanh_f(g0[2]);
      cst[0] = cc; hv[0] = sigm(g0[3])*tanh_f(cc);
      cc = sigm(g1[1])*cst[1] + sigm(g1[0])*tanh_f(g1[2]);
      cst[1] = cc; hv[1] = sigm(g1[3])*tanh_f(cc);

      #pragma unroll
      for (int q=0; q<2; ++q){
        int r = r0 + q;
        short hb = f2bf(hv[q]);
        *(short*)((char*)hbuf + (rd^1)*4096 + r*256 + ((c*2) ^ (r<<4))) = hb;
        *(short*)((char*)ab + ((s>>2)&1)*8192 + ((s&3)*NS + r)*256
                  + ((c*2) ^ (r<<4))) = hb;
      }
      bar_lds();
      if ((s&3) == 3)
        flush4(ab + ((s>>2)&1)*8192, h1, ch*CH + (s-3), dir, BR, bg, tid);
    }
    bar_lds();   // protect last flush reads before next chunk's staging writes
  }
}

// ================= attention scores =================
__global__ __launch_bounds__(256,2) void scores_kernel(
    const uint16_t* __restrict__ h1, const float* __restrict__ Wa1,
    const float* __restrict__ ba1, const float* __restrict__ Wa2,
    const float* __restrict__ ba2, float* __restrict__ scores,
    int nbb, int BR)
{
  const int bx = blockIdx.x;
  const int t = bx / nbb, bb = (bx - t*nbb) * 64;
  const int tid = threadIdx.x, w = tid>>6, l = tid&63;
  const int lm = l&15, lk = l>>4;
  __shared__ short abuf[64*256];
  __shared__ float scred[4][64];

  #pragma unroll
  for (int it=0; it<8; ++it){
    int sid = it*256 + tid, row = sid>>5, sl = sid&31;
    s16x8 v = *(const s16x8*)(h1 + ((size_t)t*BR + bb + row)*256 + sl*8);
    *(s16x8*)((char*)abuf + row*512 + ((sl ^ (row&15))<<4)) = v;
  }

  s16x8 bwa[2][8]; float b1v[2], wa2v[2];
  #pragma unroll
  for (int nt=0; nt<2; ++nt){
    int n = w*32 + nt*16 + lm;
    b1v[nt] = ba1[n]; wa2v[nt] = Wa2[n];
    #pragma unroll
    for (int kt=0; kt<8; ++kt)
      bwa[nt][kt] = cvt8(Wa1 + (size_t)n*256 + kt*32 + lk*8);
  }
  __syncthreads();

  #pragma unroll
  for (int mt=0; mt<4; ++mt){
    f32x4 a0 = {b1v[0],b1v[0],b1v[0],b1v[0]};
    f32x4 a1 = {b1v[1],b1v[1],b1v[1],b1v[1]};
    #pragma unroll
    for (int kt=0; kt<8; ++kt){
      int row = mt*16 + lm;
      s16x8 af = *(const s16x8*)((const char*)abuf + row*512 + (((kt*4+lk) ^ (row&15))<<4));
      a0 = MFMA(af, bwa[0][kt], a0);
      a1 = MFMA(af, bwa[1][kt], a1);
    }
    #pragma unroll
    for (int j=0; j<4; ++j){
      float pj = tanh_f(a0[j])*wa2v[0] + tanh_f(a1[j])*wa2v[1];
      #pragma unroll
      for (int m=1; m<16; m<<=1) pj += __shfl_xor(pj, m);
      if (lm == 0) scred[w][mt*16 + lk*4 + j] = pj;
    }
  }
  __syncthreads();
  if (tid < 64){
    float s = scred[0][tid]+scred[1][tid]+scred[2][tid]+scred[3][tid] + ba2[0];
    scores[(size_t)(bb+tid)*TT + t] = s;
  }
}

// ================= softmax over T + context =================
__global__ __launch_bounds__(256,2) void ctx_kernel(
    const uint16_t* __restrict__ h1, const float* __restrict__ scores,
    float* __restrict__ context, int BR)
{
  const int b = blockIdx.x, tid = threadIdx.x;
  __shared__ float at[TT];
  __shared__ float red[8];
  float sc = scores[(size_t)b*TT + tid];
  float m = sc;
  #pragma unroll
  for (int d=1; d<64; d<<=1) m = fmaxf(m, __shfl_xor(m, d));
  if ((tid&63)==0) red[tid>>6] = m;
  __syncthreads();
  m = fmaxf(fmaxf(red[0],red[1]), fmaxf(red[2],red[3]));
  float e = __expf(sc - m);
  float s = e;
  #pragma unroll
  for (int d=1; d<64; d<<=1) s += __shfl_xor(s, d);
  if ((tid&63)==0) red[4+(tid>>6)] = s;
  __syncthreads();
  s = red[4]+red[5]+red[6]+red[7];
  at[tid] = e / s;
  __syncthreads();

  float acc = 0.f;
  const uint16_t* hp = h1 + (size_t)b*256 + tid;
  #pragma unroll 4
  for (int t2=0; t2<TT; ++t2) acc += at[t2] * bf2f(hp[(size_t)t2*BR*256]);
  context[(size_t)b*256 + tid] = acc;
}

// ================= head =================
__global__ __launch_bounds__(128,2) void head_kernel(
    const float* __restrict__ ctx, const float* __restrict__ Wf1,
    const float* __restrict__ bf1, const float* __restrict__ g2,
    const float* __restrict__ b2, const float* __restrict__ Wf2,
    const float* __restrict__ bf2v, float* __restrict__ out, int b_off)
{
  const int b = blockIdx.x, tid = threadIdx.x;
  __shared__ float cx[256];
  __shared__ float zb[128];
  __shared__ float red[4];
  cx[tid]       = ctx[(size_t)b*256 + tid];
  cx[128+tid]   = ctx[(size_t)b*256 + 128 + tid];
  __syncthreads();
  float y = bf1[tid];
  const float* wr = Wf1 + (size_t)tid*256;
  #pragma unroll 8
  for (int k=0; k<256; ++k) y += cx[k]*wr[k];
  float s = y;
  #pragma unroll
  for (int d=1; d<64; d<<=1) s += __shfl_xor(s, d);
  if ((tid&63)==0) red[tid>>6] = s;
  __syncthreads();
  float mu = (red[0]+red[1])*(1.f/128.f);
  float dv = y - mu;
  float q = dv*dv;
  #pragma unroll
  for (int d=1; d<64; d<<=1) q += __shfl_xor(q, d);
  if ((tid&63)==0) red[2+(tid>>6)] = q;
  __syncthreads();
  float var = (red[2]+red[3])*(1.f/128.f);
  float z = dv*rsqrtf(var + 1e-5f)*g2[tid] + b2[tid];
  z = fmaxf(z, 0.f);
  zb[tid] = z;
  __syncthreads();
  if (tid < 5){
    float o = bf2v[tid];
    const float* wp = Wf2 + (size_t)tid*128;
    for (int k=0; k<128; ++k) o += zb[k]*wp[k];
    out[(size_t)(b_off + b)*5 + tid] = o;
  }
}

extern "C" void kernel_launch(void* const* d_in, const int* in_sizes, int n_in,
                              void* d_out, int out_size, void* d_ws, size_t ws_size,
                              hipStream_t stream)
{
  const float* x    = (const float*)d_in[0];
  const float* ln_g = (const float*)d_in[1];
  const float* ln_b = (const float*)d_in[2];
  const float* Wih0 = (const float*)d_in[3];
  const float* Whh0 = (const float*)d_in[4];
  const float* bih0 = (const float*)d_in[5];
  const float* bhh0 = (const float*)d_in[6];
  const float* Wih1 = (const float*)d_in[7];
  const float* Whh1 = (const float*)d_in[8];
  const float* bih1 = (const float*)d_in[9];
  const float* bhh1 = (const float*)d_in[10];
  const float* Wa1  = (const float*)d_in[11];
  const float* ba1  = (const float*)d_in[12];
  const float* Wa2  = (const float*)d_in[13];
  const float* ba2  = (const float*)d_in[14];
  const float* Wf1  = (const float*)d_in[15];
  const float* bf1  = (const float*)d_in[16];
  const float* ln2g = (const float*)d_in[17];
  const float* ln2b = (const float*)d_in[18];
  const float* Wf2  = (const float*)d_in[19];
  const float* bf2  = (const float*)d_in[20];
  float* out = (float*)d_out;

  char* wsb = (char*)d_ws;
  const size_t HBf = (size_t)TT*1024*256*2;   // 134,217,728

  prep_wih1<<<128, 256, 0, stream>>>(Wih1);

  if (ws_size >= 2*HBf){
    // ---------- FULL: whole batch in one pass; scores/ctx alias dead h0 ----------
    uint16_t* h0 = (uint16_t*)wsb;
    uint16_t* h1 = (uint16_t*)(wsb + HBf);
    float* scoresP = (float*)wsb;
    float* ctxP    = (float*)(wsb + (size_t)1024*TT*4);

    lstm0_kernel<<<256, 512, 0, stream>>>(x, ln_g, ln_b, Wih0, Whh0, bih0, bhh0,
                                          h0, 128, 1024, 0);
    lstm1_kernel<<<256, 512, 0, stream>>>(h0, Whh1, bih1, bhh1, h1, 128, 1024);
    scores_kernel<<<TT*16, 256, 0, stream>>>(h1, Wa1, ba1, Wa2, ba2, scoresP, 16, 1024);
    ctx_kernel   <<<1024, 256, 0, stream>>>(h1, scoresP, ctxP, 1024);
    head_kernel  <<<1024, 128, 0, stream>>>(ctxP, Wf1, bf1, ln2g, ln2b, Wf2, bf2, out, 0);
  } else {
    // ---------- fallback: rounds of BR samples ----------
    int BR = 512;
    while (BR > 64){
      size_t HB = (size_t)TT*BR*256*2;
      if (2*HB + 2*((size_t)BR*256*4) <= ws_size) break;
      BR >>= 1;
    }
    const size_t HB = (size_t)TT*BR*256*2;
    uint16_t* h0 = (uint16_t*)wsb;
    uint16_t* h1 = (uint16_t*)(wsb + HB);
    float* scoresP = (float*)(wsb + 2*HB);
    float* ctxP    = (float*)(wsb + 2*HB + (size_t)BR*256*4);
    const int nb = BR/NS;

    for (int b_off = 0; b_off < 1024; b_off += BR){
      lstm0_kernel<<<2*nb, 512, 0, stream>>>(x, ln_g, ln_b, Wih0, Whh0, bih0, bhh0,
                                             h0, nb, BR, b_off);
      lstm1_kernel<<<2*nb, 512, 0, stream>>>(h0, Whh1, bih1, bhh1, h1, nb, BR);
      scores_kernel<<<TT*(BR/64), 256, 0, stream>>>(h1, Wa1, ba1, Wa2, ba2, scoresP,
                                                    BR/64, BR);
      ctx_kernel   <<<BR, 256, 0, stream>>>(h1, scoresP, ctxP, BR);
      head_kernel  <<<BR, 128, 0, stream>>>(ctxP, Wf1, bf1, ln2g, ln2b, Wf2, bf2,
                                            out, b_off);
    }
  }
}

// Round 9
// 755.719 us; speedup vs baseline: 3.5978x; 1.2424x over previous
//
#include <hip/hip_runtime.h>
#include <stdint.h>

#define TT 256
#define NS 8
#define CH 8

typedef __attribute__((ext_vector_type(4))) float f32x4;
typedef __attribute__((ext_vector_type(8))) short s16x8;
typedef __attribute__((ext_vector_type(2))) unsigned int u32x2;

#define DEV static __device__ __forceinline__

// prepped bf16 Wih1 fragments: [dir][ntg(32)][kt(8)][lane(64)][8]
__device__ uint16_t g_W1f[2*32*8*64*8];

DEV short f2bf(float f){
  union{float f; uint32_t u;} v; v.f = f;
  uint32_t r = v.u + 0x7fffu + ((v.u>>16)&1u);
  return (short)(r>>16);
}
DEV float bf2f(uint32_t u16){
  union{uint32_t u; float f;} v; v.u = u16<<16; return v.f;
}
DEV uint32_t pk2(float a, float b){
  return (uint32_t)(uint16_t)f2bf(a) | ((uint32_t)(uint16_t)f2bf(b)<<16);
}
DEV float rcpf(float x){ return __builtin_amdgcn_rcpf(x); }
DEV float sigm(float x){ return rcpf(1.f + __expf(-x)); }
DEV float tanh_f(float x){ float e = __expf(2.f*x); return 1.f - 2.f*rcpf(e+1.f); }
DEV f32x4 MFMA(s16x8 a, s16x8 b, f32x4 c){
  return __builtin_amdgcn_mfma_f32_16x16x32_bf16(a, b, c, 0, 0, 0);
}
DEV s16x8 cvt8(const float* p){
  f32x4 a = *(const f32x4*)p;
  f32x4 b = *(const f32x4*)(p+4);
  s16x8 o;
  o[0]=f2bf(a[0]); o[1]=f2bf(a[1]); o[2]=f2bf(a[2]); o[3]=f2bf(a[3]);
  o[4]=f2bf(b[0]); o[5]=f2bf(b[1]); o[6]=f2bf(b[2]); o[7]=f2bf(b[3]);
  return o;
}
// barrier that drains LDS only (global stores/loads stay in flight)
DEV void bar_lds(){
  asm volatile("s_waitcnt lgkmcnt(0)" ::: "memory");
  __builtin_amdgcn_s_barrier();
}

// flush one step's h (8 rows x 128 cols bf16) straight from a 4KB hbuf buffer.
// hbuf swizzle: h[r][c] at byte r*256 + ((c*2) ^ (r<<4)); 128 threads, 16B each.
DEV void flush_step(const short* hb, uint16_t* __restrict__ hdst, int tp,
                    int dir, int BR, int bg, int tid){
  if (tid < 128){
    int row = tid >> 4, part = tid & 15;
    int tg = dir ? (TT-1-tp) : tp;
    s16x8 v = *(const s16x8*)((const char*)hb + row*256 + (((part ^ row)&15)<<4));
    *(s16x8*)(hdst + ((size_t)tg*BR + bg*NS + row)*256 + dir*128 + part*8) = v;
  }
}

// ---------------- Wih1 -> bf16 B-fragment layout ----------------
__global__ __launch_bounds__(256) void prep_wih1(const float* __restrict__ Wih1)
{
  int tid = blockIdx.x*256 + threadIdx.x;   // 32768 total
  int l = tid & 63, kt = (tid>>6)&7, ntg = (tid>>9)&31, dir = (tid>>14)&1;
  int lm = l&15, lk = l>>4;
  int n = ntg*16 + lm;
  s16x8 o = cvt8(Wih1 + ((size_t)(dir*512 + n))*256 + kt*32 + lk*8);
  *(s16x8*)(&g_W1f[(size_t)tid*8]) = o;
}

// ================= BiLSTM layer 0 (LN fused; 6 -> 128/dir), NS=8 =================
__global__ __launch_bounds__(512,2) void lstm0_kernel(
    const float* __restrict__ x, const float* __restrict__ lng,
    const float* __restrict__ lnb,
    const float* __restrict__ Wih0, const float* __restrict__ Whh0,
    const float* __restrict__ bih0, const float* __restrict__ bhh0,
    uint16_t* __restrict__ h0, int nb, int BR, int b_off)
{
  const int dir = blockIdx.x / nb, bg = blockIdx.x % nb;
  const int tid = threadIdx.x, w = tid>>6, l = tid&63;
  const int lm = l&15, lk = l>>4;
  const int gb = b_off + bg*NS;

  __shared__ short hbuf[2][2048];     // 8 KB, XOR(row<<4) swizzle
  __shared__ short xnbf[TT*NS*8];     // 32 KB: [t][r][8] bf16 (K=6 padded)
  __shared__ short bxs[8*4*64*8];     // 32 KB: input-proj fragments per (w,G,l)

  for (int i=tid; i<4096; i+=512) ((short*)hbuf)[i] = 0;

  // LN fused staging
  #pragma unroll
  for (int it=0; it<4; ++it){
    int pr = it*512 + tid;
    int r = pr >> 8, t = pr & 255;
    const float* px = x + ((size_t)(gb+r)*TT + t)*6;
    float v[6]; float mu=0.f, var=0.f;
    #pragma unroll
    for (int d=0; d<6; ++d){ v[d]=px[d]; mu+=v[d]; }
    mu *= (1.f/6.f);
    #pragma unroll
    for (int d=0; d<6; ++d){ float dd=v[d]-mu; var+=dd*dd; }
    float rs = rsqrtf(var*(1.f/6.f) + 1e-5f);
    s16x8 vv;
    #pragma unroll
    for (int d=0; d<6; ++d) vv[d] = f2bf((v[d]-mu)*rs*lng[d] + lnb[d]);
    vv[6]=0; vv[7]=0;
    *(s16x8*)&xnbf[(t*NS + r)*8] = vv;
  }

  const int c = w*16 + lm;
  s16x8 bw[4][4];
  float biasc[4];
  #pragma unroll
  for (int G=0; G<4; ++G){
    const int n = G*128 + c;
    biasc[G] = bih0[dir*512+n] + bhh0[dir*512+n];
    #pragma unroll
    for (int kt=0; kt<4; ++kt)
      bw[G][kt] = cvt8(Whh0 + ((size_t)(dir*512+n))*128 + kt*32 + lk*8);
    s16x8 tx;
    #pragma unroll
    for (int j=0; j<8; ++j){
      int k = lk*8 + j;
      tx[j] = (k<6) ? f2bf(Wih0[(size_t)(dir*512+n)*6 + k]) : (short)0;
    }
    *(s16x8*)&bxs[((w*4+G)*64 + l)*8] = tx;   // park in LDS (saves 16 VGPRs)
  }

  const int r0 = ((l>>4)&1)*4 + ((l<32)?0:2);
  float cst[2] = {0.f, 0.f};
  __syncthreads();

  for (int t=0; t<TT; ++t){
    const int tt = dir ? (TT-1-t) : t;
    const int rd = t & 1;
    s16x8 ah[4];
    #pragma unroll
    for (int kt=0; kt<4; ++kt){
      int off = rd*4096 + lm*256 + ((kt*64 + lk*16) ^ (lm<<4));
      ah[kt] = *(const s16x8*)((const char*)hbuf + off);
    }
    s16x8 ax = {0,0,0,0,0,0,0,0};
    if (l < 8) ax = *(const s16x8*)&xnbf[(tt*NS + l)*8];

    f32x4 acc[4];
    #pragma unroll
    for (int G=0; G<4; ++G){
      f32x4 a = {0.f,0.f,0.f,0.f};
      #pragma unroll
      for (int kt=0; kt<4; ++kt) a = MFMA(ah[kt], bw[G][kt], a);
      s16x8 bx = *(const s16x8*)&bxs[((w*4+G)*64 + l)*8];
      a = MFMA(ax, bx, a);
      acc[G] = a;
    }

    float g0[4], g1[4];
    #pragma unroll
    for (int G=0; G<4; ++G){
      float o2 = __shfl(acc[G][2], l & 31);
      float o3 = __shfl(acc[G][3], l & 31);
      g0[G] = ((l<32) ? acc[G][0] : o2) + biasc[G];
      g1[G] = ((l<32) ? acc[G][1] : o3) + biasc[G];
    }
    float hv[2];
    {
      float cc = sigm(g0[1])*cst[0] + sigm(g0[0])*tanh_f(g0[2]);
      cst[0] = cc; hv[0] = sigm(g0[3])*tanh_f(cc);
      cc = sigm(g1[1])*cst[1] + sigm(g1[0])*tanh_f(g1[2]);
      cst[1] = cc; hv[1] = sigm(g1[3])*tanh_f(cc);
    }

    #pragma unroll
    for (int q=0; q<2; ++q){
      int r = r0 + q;
      *(short*)((char*)hbuf + (rd^1)*4096 + r*256 + ((c*2) ^ (r<<4))) = f2bf(hv[q]);
    }
    // flush previous step's h straight from hbuf[rd] (read-only this step)
    if (t > 0)
      flush_step(hbuf[rd], h0, t-1, dir, BR, bg, tid);
    bar_lds();
  }
  flush_step(hbuf[0], h0, TT-1, dir, BR, bg, tid);   // h(255) sits in hbuf[0]
}

// ============ BiLSTM layer 1 (256 -> 128/dir), fused xp, NS=8, CH=8 ============
__global__ __launch_bounds__(512,2) void lstm1_kernel(
    const uint16_t* __restrict__ h0,
    const float* __restrict__ Whh1, const float* __restrict__ bih1,
    const float* __restrict__ bhh1, uint16_t* __restrict__ h1,
    int nb, int BR)
{
  const int dir = blockIdx.x / nb, bg = blockIdx.x % nb;
  const int tid = threadIdx.x, w = tid>>6, l = tid&63;
  const int lm = l&15, lk = l>>4;

  __shared__ short hbuf[2][2048];     // 8 KB
  __shared__ short abuf[2][16384];    // 64 KB: 64 rows (8 steps x 8 samples) x 256, dbuf
  __shared__ u32x2 xpbuf[8192];       // 64 KB: [w][G][mt][lane] packed-bf16 xp

  for (int i=tid; i<4096; i+=512) ((short*)hbuf)[i] = 0;

  const int c = w*16 + lm;
  s16x8 bw[4][4];
  float biasv[4];
  #pragma unroll
  for (int G=0; G<4; ++G){
    const int n = G*128 + c;
    biasv[G] = bih1[dir*512+n] + bhh1[dir*512+n];
    #pragma unroll
    for (int kt=0; kt<4; ++kt)
      bw[G][kt] = cvt8(Whh1 + ((size_t)(dir*512+n))*128 + kt*32 + lk*8);
  }

  const int r0 = ((l>>4)&1)*4 + ((l<32)?0:2);
  float cst[2] = {0.f,0.f};
  s16x8 vst[4];

  // prologue: stage chunk 0 (rows = s*8 + b)
  #pragma unroll
  for (int it=0; it<4; ++it){
    int sid = it*512 + tid, row = sid>>5, sl = sid&31, s = row>>3, b = row&7;
    int tg = dir ? (TT-1-s) : s;
    vst[it] = *(const s16x8*)(h0 + ((size_t)tg*BR + bg*NS + b)*256 + sl*8);
  }
  #pragma unroll
  for (int it=0; it<4; ++it){
    int sid = it*512 + tid, row = sid>>5, sl = sid&31;
    *(s16x8*)((char*)abuf + row*512 + ((sl ^ (row&15))<<4)) = vst[it];
  }
  __syncthreads();

  for (int ch=0; ch<TT/CH; ++ch){
    const int cur = ch & 1;
    const char* ab = (const char*)abuf + cur*32768;

    // issue next chunk's loads early (land during phase A)
    if (ch < TT/CH-1){
      #pragma unroll
      for (int it=0; it<4; ++it){
        int sid = it*512 + tid, row = sid>>5, sl = sid&31, s = row>>3, b = row&7;
        int ts = (ch+1)*CH + s;
        int tg = dir ? (TT-1-ts) : ts;
        vst[it] = *(const s16x8*)(h0 + ((size_t)tg*BR + bg*NS + b)*256 + sl*8);
      }
    }

    // ---- phase A: xp for CH steps -> LDS ----
    #pragma unroll
    for (int G=0; G<4; ++G){
      f32x4 acc[4];
      #pragma unroll
      for (int mt=0; mt<4; ++mt) acc[mt] = (f32x4){biasv[G],biasv[G],biasv[G],biasv[G]};
      #pragma unroll
      for (int kt=0; kt<8; ++kt){
        s16x8 bfr = *(const s16x8*)(&g_W1f[(((size_t)(dir*32 + G*8 + w)*8 + kt)*64 + l)*8]);
        #pragma unroll
        for (int mt=0; mt<4; ++mt){
          int row = mt*16 + lm;
          s16x8 afr = *(const s16x8*)(ab + row*512 + (((kt*4+lk) ^ (row&15))<<4));
          acc[mt] = MFMA(afr, bfr, acc[mt]);
        }
      }
      #pragma unroll
      for (int mt=0; mt<4; ++mt){
        u32x2 pw;
        pw[0] = pk2(acc[mt][0], acc[mt][1]);
        pw[1] = pk2(acc[mt][2], acc[mt][3]);
        xpbuf[((w*4+G)*4+mt)*64 + l] = pw;
      }
    }

    // write staged regs -> other abuf (its readers finished last chunk)
    if (ch < TT/CH-1){
      char* ab2 = (char*)abuf + (cur^1)*32768;
      #pragma unroll
      for (int it=0; it<4; ++it){
        int sid = it*512 + tid, row = sid>>5, sl = sid&31;
        *(s16x8*)(ab2 + row*512 + ((sl ^ (row&15))<<4)) = vst[it];
      }
    }
    bar_lds();

    // ---- phase B: CH recurrent steps ----
    #pragma unroll
    for (int s=0; s<CH; ++s){
      const int gs = ch*CH + s;
      const int rd = gs & 1;
      // holder lane of xp rows (s*8 + lk*4 + j): ((s&1)*2+lk)*16 + lm
      const int lane2 = ((((s&1)<<1) + lk)<<4) + lm;

      f32x4 acc4[4];
      #pragma unroll
      for (int G=0; G<4; ++G){
        u32x2 pw = xpbuf[((w*4+G)*4 + (s>>1))*64 + lane2];
        acc4[G] = (f32x4){bf2f(pw[0]&0xffffu), bf2f(pw[0]>>16),
                          bf2f(pw[1]&0xffffu), bf2f(pw[1]>>16)};
      }

      s16x8 ah[4];
      #pragma unroll
      for (int kt=0; kt<4; ++kt){
        int off = rd*4096 + lm*256 + ((kt*64 + lk*16) ^ (lm<<4));
        ah[kt] = *(const s16x8*)((const char*)hbuf + off);
      }
      #pragma unroll
      for (int G=0; G<4; ++G){
        #pragma unroll
        for (int kt=0; kt<4; ++kt)
          acc4[G] = MFMA(ah[kt], bw[G][kt], acc4[G]);
      }

      float g0[4], g1[4];
      #pragma unroll
      for (int G=0; G<4; ++G){
        float o2 = __shfl(acc4[G][2], l & 31);
        float o3 = __shfl(acc4[G][3], l & 31);
        g0[G] = (l<32) ? acc4[G][0] : o2;
        g1[G] = (l<32) ? acc4[G][1] : o3;
      }
      float hv[2];
      float cc = sigm(g0[1])*cst[0] + sigm(g0[0])*tanh_f(g0[2]);
      cst[0] = cc; hv[0] = sigm(g0[3])*tanh_f(cc);
      cc = sigm(g1[1])*cst[1] + sigm(g1[0])*tanh_f(g1[2]);
      cst[1] = cc; hv[1] = sigm(g1[3])*tanh_f(cc);

      #pragma unroll
      for (int q=0; q<2; ++q){
        int r = r0 + q;
        *(short*)((char*)hbuf + (rd^1)*4096 + r*256 + ((c*2) ^ (r<<4))) = f2bf(hv[q]);
      }
      if (gs > 0)
        flush_step(hbuf[rd], h1, gs-1, dir, BR, bg, tid);
      bar_lds();
    }
  }
  flush_step(hbuf[0], h1, TT-1, dir, BR, bg, tid);   // h(255) sits in hbuf[0]
}

// ================= attention scores =================
__global__ __launch_bounds__(256,2) void scores_kernel(
    const uint16_t* __restrict__ h1, const float* __restrict__ Wa1,
    const float* __restrict__ ba1, const float* __restrict__ Wa2,
    const float* __restrict__ ba2, float* __restrict__ scores,
    int nbb, int BR)
{
  const int bx = blockIdx.x;
  const int t = bx / nbb, bb = (bx - t*nbb) * 64;
  const int tid = threadIdx.x, w = tid>>6, l = tid&63;
  const int lm = l&15, lk = l>>4;
  __shared__ short abuf[64*256];
  __shared__ float scred[4][64];

  #pragma unroll
  for (int it=0; it<8; ++it){
    int sid = it*256 + tid, row = sid>>5, sl = sid&31;
    s16x8 v = *(const s16x8*)(h1 + ((size_t)t*BR + bb + row)*256 + sl*8);
    *(s16x8*)((char*)abuf + row*512 + ((sl ^ (row&15))<<4)) = v;
  }

  s16x8 bwa[2][8]; float b1v[2], wa2v[2];
  #pragma unroll
  for (int nt=0; nt<2; ++nt){
    int n = w*32 + nt*16 + lm;
    b1v[nt] = ba1[n]; wa2v[nt] = Wa2[n];
    #pragma unroll
    for (int kt=0; kt<8; ++kt)
      bwa[nt][kt] = cvt8(Wa1 + (size_t)n*256 + kt*32 + lk*8);
  }
  __syncthreads();

  #pragma unroll
  for (int mt=0; mt<4; ++mt){
    f32x4 a0 = {b1v[0],b1v[0],b1v[0],b1v[0]};
    f32x4 a1 = {b1v[1],b1v[1],b1v[1],b1v[1]};
    #pragma unroll
    for (int kt=0; kt<8; ++kt){
      int row = mt*16 + lm;
      s16x8 af = *(const s16x8*)((const char*)abuf + row*512 + (((kt*4+lk) ^ (row&15))<<4));
      a0 = MFMA(af, bwa[0][kt], a0);
      a1 = MFMA(af, bwa[1][kt], a1);
    }
    #pragma unroll
    for (int j=0; j<4; ++j){
      float pj = tanh_f(a0[j])*wa2v[0] + tanh_f(a1[j])*wa2v[1];
      #pragma unroll
      for (int m=1; m<16; m<<=1) pj += __shfl_xor(pj, m);
      if (lm == 0) scred[w][mt*16 + lk*4 + j] = pj;
    }
  }
  __syncthreads();
  if (tid < 64){
    float s = scred[0][tid]+scred[1][tid]+scred[2][tid]+scred[3][tid] + ba2[0];
    scores[(size_t)(bb+tid)*TT + t] = s;
  }
}

// ================= softmax over T + context =================
__global__ __launch_bounds__(256,2) void ctx_kernel(
    const uint16_t* __restrict__ h1, const float* __restrict__ scores,
    float* __restrict__ context, int BR)
{
  const int b = blockIdx.x, tid = threadIdx.x;
  __shared__ float at[TT];
  __shared__ float red[8];
  float sc = scores[(size_t)b*TT + tid];
  float m = sc;
  #pragma unroll
  for (int d=1; d<64; d<<=1) m = fmaxf(m, __shfl_xor(m, d));
  if ((tid&63)==0) red[tid>>6] = m;
  __syncthreads();
  m = fmaxf(fmaxf(red[0],red[1]), fmaxf(red[2],red[3]));
  float e = __expf(sc - m);
  float s = e;
  #pragma unroll
  for (int d=1; d<64; d<<=1) s += __shfl_xor(s, d);
  if ((tid&63)==0) red[4+(tid>>6)] = s;
  __syncthreads();
  s = red[4]+red[5]+red[6]+red[7];
  at[tid] = e * rcpf(s);
  __syncthreads();

  float acc = 0.f;
  const uint16_t* hp = h1 + (size_t)b*256 + tid;
  #pragma unroll 8
  for (int t2=0; t2<TT; ++t2) acc += at[t2] * bf2f(hp[(size_t)t2*BR*256]);
  context[(size_t)b*256 + tid] = acc;
}

// ================= head =================
__global__ __launch_bounds__(128,2) void head_kernel(
    const float* __restrict__ ctx, const float* __restrict__ Wf1,
    const float* __restrict__ bf1, const float* __restrict__ g2,
    const float* __restrict__ b2, const float* __restrict__ Wf2,
    const float* __restrict__ bf2v, float* __restrict__ out, int b_off)
{
  const int b = blockIdx.x, tid = threadIdx.x;
  __shared__ float cx[256];
  __shared__ float zb[128];
  __shared__ float red[4];
  cx[tid]       = ctx[(size_t)b*256 + tid];
  cx[128+tid]   = ctx[(size_t)b*256 + 128 + tid];
  __syncthreads();
  float y = bf1[tid];
  const float* wr = Wf1 + (size_t)tid*256;
  #pragma unroll 8
  for (int k=0; k<256; ++k) y += cx[k]*wr[k];
  float s = y;
  #pragma unroll
  for (int d=1; d<64; d<<=1) s += __shfl_xor(s, d);
  if ((tid&63)==0) red[tid>>6] = s;
  __syncthreads();
  float mu = (red[0]+red[1])*(1.f/128.f);
  float dv = y - mu;
  float q = dv*dv;
  #pragma unroll
  for (int d=1; d<64; d<<=1) q += __shfl_xor(q, d);
  if ((tid&63)==0) red[2+(tid>>6)] = q;
  __syncthreads();
  float var = (red[2]+red[3])*(1.f/128.f);
  float z = dv*rsqrtf(var + 1e-5f)*g2[tid] + b2[tid];
  z = fmaxf(z, 0.f);
  zb[tid] = z;
  __syncthreads();
  if (tid < 5){
    float o = bf2v[tid];
    const float* wp = Wf2 + (size_t)tid*128;
    for (int k=0; k<128; ++k) o += zb[k]*wp[k];
    out[(size_t)(b_off + b)*5 + tid] = o;
  }
}

extern "C" void kernel_launch(void* const* d_in, const int* in_sizes, int n_in,
                              void* d_out, int out_size, void* d_ws, size_t ws_size,
                              hipStream_t stream)
{
  const float* x    = (const float*)d_in[0];
  const float* ln_g = (const float*)d_in[1];
  const float* ln_b = (const float*)d_in[2];
  const float* Wih0 = (const float*)d_in[3];
  const float* Whh0 = (const float*)d_in[4];
  const float* bih0 = (const float*)d_in[5];
  const float* bhh0 = (const float*)d_in[6];
  const float* Wih1 = (const float*)d_in[7];
  const float* Whh1 = (const float*)d_in[8];
  const float* bih1 = (const float*)d_in[9];
  const float* bhh1 = (const float*)d_in[10];
  const float* Wa1  = (const float*)d_in[11];
  const float* ba1  = (const float*)d_in[12];
  const float* Wa2  = (const float*)d_in[13];
  const float* ba2  = (const float*)d_in[14];
  const float* Wf1  = (const float*)d_in[15];
  const float* bf1  = (const float*)d_in[16];
  const float* ln2g = (const float*)d_in[17];
  const float* ln2b = (const float*)d_in[18];
  const float* Wf2  = (const float*)d_in[19];
  const float* bf2  = (const float*)d_in[20];
  float* out = (float*)d_out;

  char* wsb = (char*)d_ws;
  const size_t HBf = (size_t)TT*1024*256*2;   // 134,217,728

  prep_wih1<<<128, 256, 0, stream>>>(Wih1);

  if (ws_size >= 2*HBf){
    // ---------- FULL: whole batch in one pass; scores/ctx alias dead h0 ----------
    uint16_t* h0 = (uint16_t*)wsb;
    uint16_t* h1 = (uint16_t*)(wsb + HBf);
    float* scoresP = (float*)wsb;
    float* ctxP    = (float*)(wsb + (size_t)1024*TT*4);

    lstm0_kernel<<<256, 512, 0, stream>>>(x, ln_g, ln_b, Wih0, Whh0, bih0, bhh0,
                                          h0, 128, 1024, 0);
    lstm1_kernel<<<256, 512, 0, stream>>>(h0, Whh1, bih1, bhh1, h1, 128, 1024);
    scores_kernel<<<TT*16, 256, 0, stream>>>(h1, Wa1, ba1, Wa2, ba2, scoresP, 16, 1024);
    ctx_kernel   <<<1024, 256, 0, stream>>>(h1, scoresP, ctxP, 1024);
    head_kernel  <<<1024, 128, 0, stream>>>(ctxP, Wf1, bf1, ln2g, ln2b, Wf2, bf2, out, 0);
  } else {
    // ---------- fallback: rounds of BR samples ----------
    int BR = 512;
    while (BR > 64){
      size_t HB = (size_t)TT*BR*256*2;
      if (2*HB + 2*((size_t)BR*256*4) <= ws_size) break;
      BR >>= 1;
    }
    const size_t HB = (size_t)TT*BR*256*2;
    uint16_t* h0 = (uint16_t*)wsb;
    uint16_t* h1 = (uint16_t*)(wsb + HB);
    float* scoresP = (float*)(wsb + 2*HB);
    float* ctxP    = (float*)(wsb + 2*HB + (size_t)BR*256*4);
    const int nb = BR/NS;

    for (int b_off = 0; b_off < 1024; b_off += BR){
      lstm0_kernel<<<2*nb, 512, 0, stream>>>(x, ln_g, ln_b, Wih0, Whh0, bih0, bhh0,
                                             h0, nb, BR, b_off);
      lstm1_kernel<<<2*nb, 512, 0, stream>>>(h0, Whh1, bih1, bhh1, h1, nb, BR);
      scores_kernel<<<TT*(BR/64), 256, 0, stream>>>(h1, Wa1, ba1, Wa2, ba2, scoresP,
                                                    BR/64, BR);
      ctx_kernel   <<<BR, 256, 0, stream>>>(h1, scoresP, ctxP, BR);
      head_kernel  <<<BR, 128, 0, stream>>>(ctxP, Wf1, bf1, ln2g, ln2b, Wf2, bf2,
                                            out, b_off);
    }
  }
}